// Round 8
// baseline (38575.601 us; speedup 1.0000x reference)
//
#include <hip/hip_runtime.h>
#include <hip/hip_cooperative_groups.h>

// Problem constants (fixed by setup_inputs / reference)
constexpr int   NROWS   = 131072;
constexpr int   KCOLS   = 512;
constexpr int   KP1     = 513;   // + dummy column
constexpr float PA      = 1.0f / 131072.0f;
constexpr float PB_REAL = 0.5f / 512.0f;
constexpr float PB_DUM  = 0.5f;
constexpr float FI      = (float)(1.0 / 1.1); // GAMMA/(GAMMA+EPSILON)
constexpr float STOPERR = 1e-6f;
constexpr int   MAXIT   = 1000;
constexpr float LOG2E   = 1.4426950408889634f;
constexpr float CQ      = 10.0f * LOG2E;      // (1/EPSILON)*log2(e)
constexpr float LN2     = 0.6931471805599453f;

constexpr int THREADS = 1024;
constexpr int WPB     = THREADS / 64;     // 16 waves per block

// Workspace layout (floats). Total ~1.06 MB (well under proven 1.58 MB).
constexpr size_t OFF_LSE = 0;                        // [NROWS] row logsumexp
constexpr size_t OFF_A   = (size_t)NROWS;            // [NROWS] scaling a
constexpr int    KPAD    = 516;                      // LDS row stride (floats)
constexpr size_t OFF_B0  = 2 * (size_t)NROWS;        // [KPAD] b ping     (sc-only)
constexpr size_t OFF_B1  = OFF_B0 + KPAD;            // [KPAD] b pong     (sc-only)
constexpr size_t OFF_BF  = OFF_B0 + 2 * KPAD;        // [KPAD] b final    (normal)
constexpr size_t OFF_D0  = OFF_B0 + 3 * KPAD;        // [KPAD] delta ping (sc-only)
constexpr size_t OFF_D1  = OFF_B0 + 4 * KPAD;        // [KPAD] delta pong (sc-only)

// Big scratch in the d_out tail (d_out = 256 MiB):
//   [0, 128 MiB)   qhi  ushort[NROWS*KCOLS]
//   [128, 192 MiB) qlo  uchar[NROWS*KCOLS]
//   [192 MiB, ...) colp float[KP1 * 512] transposed (<= 1.1 MB)
//   [200 MiB, ...) barrier words (cnt, gen)
constexpr size_t QLO_BYTE_OFF  = (size_t)NROWS * KCOLS * 2;   // 128 MiB
constexpr size_t COLP_BYTE_OFF = 192ull * 1024 * 1024;
constexpr size_t BAR_BYTE_OFF  = 200ull * 1024 * 1024;

__device__ __forceinline__ float waveReduceSum(float v) {
#pragma unroll
  for (int s = 32; s >= 1; s >>= 1) v += __shfl_xor(v, s);
  return v;
}
__device__ __forceinline__ float waveReduceMax(float v) {
#pragma unroll
  for (int s = 32; s >= 1; s >>= 1) v = fmaxf(v, __shfl_xor(v, s));
  return v;
}

// device-coherent (agent-scope) accessors: bypass non-coherent L2, hit LLC.
__device__ __forceinline__ float scload(const float* p) {
  return __hip_atomic_load(p, __ATOMIC_RELAXED, __HIP_MEMORY_SCOPE_AGENT);
}
__device__ __forceinline__ void scstore(float* p, float v) {
  __hip_atomic_store(p, v, __ATOMIC_RELAXED, __HIP_MEMORY_SCOPE_AGENT);
}

// reconstruct 8 f32 Q values (24-bit: hi ushort + lo byte) from packed loads
__device__ __forceinline__ void unpack8(const uint4 h, const uint2 l, float q[8]) {
  q[0] = __uint_as_float((h.x << 16)         | ((l.x << 8) & 0xff00u));
  q[1] = __uint_as_float((h.x & 0xffff0000u) | ( l.x       & 0xff00u));
  q[2] = __uint_as_float((h.y << 16)         | ((l.x >> 8) & 0xff00u));
  q[3] = __uint_as_float((h.y & 0xffff0000u) | ((l.x >> 16)& 0xff00u));
  q[4] = __uint_as_float((h.z << 16)         | ((l.y << 8) & 0xff00u));
  q[5] = __uint_as_float((h.z & 0xffff0000u) | ( l.y       & 0xff00u));
  q[6] = __uint_as_float((h.w << 16)         | ((l.y >> 8) & 0xff00u));
  q[7] = __uint_as_float((h.w & 0xffff0000u) | ((l.y >> 16)& 0xff00u));
}

// ---------------------------------------------------------------------------
// Kernel 1: per-row logsumexp + 24-bit Q planes (into d_out) + state init.
// ---------------------------------------------------------------------------
__global__ __launch_bounds__(1024) void lse_q_init_kernel(
    const float* __restrict__ logits, float* __restrict__ ws,
    unsigned short* __restrict__ qhi, unsigned char* __restrict__ qlo,
    unsigned* __restrict__ bar) {
  float* lse = ws + OFF_LSE;
  const int nw   = (gridDim.x * blockDim.x) >> 6;
  const int gw   = (blockIdx.x * blockDim.x + threadIdx.x) >> 6;
  const int lane = threadIdx.x & 63;

  for (int r = gw; r < NROWS; r += nw) {
    const float4* row4 = reinterpret_cast<const float4*>(logits + (size_t)r * KCOLS);
    float4 x0 = row4[lane];
    float4 x1 = row4[64 + lane];
    float m = fmaxf(fmaxf(fmaxf(x0.x, x0.y), fmaxf(x0.z, x0.w)),
                    fmaxf(fmaxf(x1.x, x1.y), fmaxf(x1.z, x1.w)));
    m = waveReduceMax(m);
    float s = exp2f((x0.x - m) * LOG2E) + exp2f((x0.y - m) * LOG2E)
            + exp2f((x0.z - m) * LOG2E) + exp2f((x0.w - m) * LOG2E)
            + exp2f((x1.x - m) * LOG2E) + exp2f((x1.y - m) * LOG2E)
            + exp2f((x1.z - m) * LOG2E) + exp2f((x1.w - m) * LOG2E);
    s = waveReduceSum(s);
    float L = m + log2f(s) * LN2;
    if (lane == 0) lse[r] = L;
    unsigned u[8];
    u[0] = __float_as_uint(exp2f((x0.x - L) * CQ)) + 0x80u;
    u[1] = __float_as_uint(exp2f((x0.y - L) * CQ)) + 0x80u;
    u[2] = __float_as_uint(exp2f((x0.z - L) * CQ)) + 0x80u;
    u[3] = __float_as_uint(exp2f((x0.w - L) * CQ)) + 0x80u;
    u[4] = __float_as_uint(exp2f((x1.x - L) * CQ)) + 0x80u;
    u[5] = __float_as_uint(exp2f((x1.y - L) * CQ)) + 0x80u;
    u[6] = __float_as_uint(exp2f((x1.z - L) * CQ)) + 0x80u;
    u[7] = __float_as_uint(exp2f((x1.w - L) * CQ)) + 0x80u;
    ushort4 hA, hB;  uchar4 lA, lB;
    hA.x = (unsigned short)(u[0] >> 16); lA.x = (unsigned char)(u[0] >> 8);
    hA.y = (unsigned short)(u[1] >> 16); lA.y = (unsigned char)(u[1] >> 8);
    hA.z = (unsigned short)(u[2] >> 16); lA.z = (unsigned char)(u[2] >> 8);
    hA.w = (unsigned short)(u[3] >> 16); lA.w = (unsigned char)(u[3] >> 8);
    hB.x = (unsigned short)(u[4] >> 16); lB.x = (unsigned char)(u[4] >> 8);
    hB.y = (unsigned short)(u[5] >> 16); lB.y = (unsigned char)(u[5] >> 8);
    hB.z = (unsigned short)(u[6] >> 16); lB.z = (unsigned char)(u[6] >> 8);
    hB.w = (unsigned short)(u[7] >> 16); lB.w = (unsigned char)(u[7] >> 8);
    *reinterpret_cast<ushort4*>(qhi + (size_t)r * KCOLS + 4 * lane)       = hA;
    *reinterpret_cast<ushort4*>(qhi + (size_t)r * KCOLS + 256 + 4 * lane) = hB;
    *reinterpret_cast<uchar4*>(qlo + (size_t)r * KCOLS + 4 * lane)        = lA;
    *reinterpret_cast<uchar4*>(qlo + (size_t)r * KCOLS + 256 + 4 * lane)  = lB;
  }
  if (blockIdx.x == 0 && threadIdx.x < KP1)
    ws[OFF_B0 + threadIdx.x] = 1.0f / 513.0f;
  if (blockIdx.x == 0 && threadIdx.x == 0) {
    bar[0]  = 0u;   // arrival counter (cumulative)
    bar[32] = 0u;   // generation
  }
}

// ---------------------------------------------------------------------------
// Kernel 2 (cooperative, custom barrier), templated on grid size NBLK.
// Phase A = r5-proven 4-row unroll (fits 64 VGPR, no spill). LDS shrunk to
// 8 rows (16.5 KB) via a two-stage wave combine so 2 blocks/CU fit.
// Per-coordinate Aitken Delta^2 every 8 iters (guarded; stop criterion stays
// the pure-map residual, so extrapolation cannot corrupt the result).
// ---------------------------------------------------------------------------
template <int NBLK>
__global__ __launch_bounds__(THREADS, 8) void sinkhorn_loop(
    const unsigned short* __restrict__ qhi, const unsigned char* __restrict__ qlo,
    float* __restrict__ ws, float* __restrict__ colp, unsigned* __restrict__ bar) {
  float* a    = ws + OFF_A;
  float* b0   = ws + OFF_B0;
  float* b1   = ws + OFF_B1;
  float* bfin = ws + OFF_BF;
  float* dl0  = ws + OFF_D0;
  float* dl1  = ws + OFF_D1;
  unsigned* cnt = bar;
  unsigned* gen = bar + 32;

  __shared__ float lds[8][KPAD];   // 8*516*4 = 16,512 B
  __shared__ float s_err;
  __shared__ int   s_nbar;
  __shared__ int   s_dead;

  const int tid  = threadIdx.x;
  const int wv   = tid >> 6;
  const int lane = tid & 63;
  const int bk   = blockIdx.x;
  const int gw   = bk * WPB + wv;        // global wave id [0, NBLK*16)
  const int NWV  = NBLK * WPB;           // total waves

  if (tid == 0) { s_nbar = 0; s_dead = 0; }
  __syncthreads();

  // Grid barrier: __syncthreads drains vmcnt before s_barrier, so retired
  // agent-scope stores are LLC-visible before arrival. (Proven r5/r7.)
  auto gridBar = [&]() {
    __syncthreads();
    if (tid == 0) {
      int nb = s_nbar;
      unsigned old = atomicAdd(cnt, 1u);
      if (old == (unsigned)(nb * NBLK + (NBLK - 1))) {
        atomicAdd(gen, 1u);
      } else if (!s_dead) {
        int spins = 0;
        while (__hip_atomic_load(gen, __ATOMIC_RELAXED, __HIP_MEMORY_SCOPE_AGENT)
               <= (unsigned)nb) {
          __builtin_amdgcn_s_sleep(1);
          if (++spins > (1 << 24)) { s_dead = 1; break; }  // fail-fast
        }
      }
      s_nbar = nb + 1;
    }
    __syncthreads();
  };

  float err = 1.0f;
  int it = 0;
  for (; it < MAXIT; ++it) {
    if (!(err > STOPERR)) break;   // NaN err also stops (matches JAX)

    const float* bcv = (it & 1) ? b1 : b0;
    float*       bnv = (it & 1) ? b0 : b1;
    float*       dcu = (it & 1) ? dl1 : dl0;   // this iter's delta
    const float* dpr = (it & 1) ? dl0 : dl1;   // previous iter's delta

    // stage current b (written remotely last iter -> agent-scope loads)
    float rb[8];
#pragma unroll
    for (int e = 0; e < 8; ++e) rb[e] = scload(&bcv[8 * lane + e]);
    float bdum = scload(&bcv[512]);

    // ---- phase A: rows, 4-row unroll (r5-proven register budget) ----
    float cp[8] = {0.f, 0.f, 0.f, 0.f, 0.f, 0.f, 0.f, 0.f};
    float adum = 0.f;
    for (int r = gw; r < NROWS; r += 4 * NWV) {
      const int r1 = r + NWV, r2 = r + 2 * NWV, r3 = r + 3 * NWV;
      uint4 h0 = ((const uint4*)(qhi + (size_t)r  * KCOLS))[lane];
      uint4 h1 = ((const uint4*)(qhi + (size_t)r1 * KCOLS))[lane];
      uint4 h2 = ((const uint4*)(qhi + (size_t)r2 * KCOLS))[lane];
      uint4 h3 = ((const uint4*)(qhi + (size_t)r3 * KCOLS))[lane];
      uint2 l0 = ((const uint2*)(qlo + (size_t)r  * KCOLS))[lane];
      uint2 l1 = ((const uint2*)(qlo + (size_t)r1 * KCOLS))[lane];
      uint2 l2 = ((const uint2*)(qlo + (size_t)r2 * KCOLS))[lane];
      uint2 l3 = ((const uint2*)(qlo + (size_t)r3 * KCOLS))[lane];
      float q0[8], q1[8], q2[8], q3[8];
      unpack8(h0, l0, q0);
      unpack8(h1, l1, q1);
      unpack8(h2, l2, q2);
      unpack8(h3, l3, q3);
      float d0 = 0.f, d1 = 0.f, d2 = 0.f, d3 = 0.f;
#pragma unroll
      for (int e = 0; e < 8; ++e) {
        d0 = fmaf(q0[e], rb[e], d0);
        d1 = fmaf(q1[e], rb[e], d1);
        d2 = fmaf(q2[e], rb[e], d2);
        d3 = fmaf(q3[e], rb[e], d3);
      }
#pragma unroll
      for (int s = 32; s >= 1; s >>= 1) {   // 4 interleaved butterflies
        d0 += __shfl_xor(d0, s);
        d1 += __shfl_xor(d1, s);
        d2 += __shfl_xor(d2, s);
        d3 += __shfl_xor(d3, s);
      }
      float ai0 = PA / (d0 + bdum);
      float ai1 = PA / (d1 + bdum);
      float ai2 = PA / (d2 + bdum);
      float ai3 = PA / (d3 + bdum);
      if (lane == 0) { a[r] = ai0; a[r1] = ai1; a[r2] = ai2; a[r3] = ai3; }
#pragma unroll
      for (int e = 0; e < 8; ++e) {
        cp[e] = fmaf(ai0, q0[e], cp[e]);
        cp[e] = fmaf(ai1, q1[e], cp[e]);
        cp[e] = fmaf(ai2, q2[e], cp[e]);
        cp[e] = fmaf(ai3, q3[e], cp[e]);
      }
      adum += (ai0 + ai1) + (ai2 + ai3);
    }
    // ---- two-stage wave combine in 8 LDS rows (16.5 KB) ----
    if (wv >= 8) {
#pragma unroll
      for (int e = 0; e < 8; ++e) lds[wv - 8][8 * lane + e] = cp[e];
      if (lane == 0) lds[wv - 8][512] = adum;
    }
    __syncthreads();
    if (wv < 8) {
#pragma unroll
      for (int e = 0; e < 8; ++e) cp[e] += lds[wv][8 * lane + e];
      if (lane == 0) adum += lds[wv][512];
    }
    __syncthreads();
    if (wv < 8) {
#pragma unroll
      for (int e = 0; e < 8; ++e) lds[wv][8 * lane + e] = cp[e];
      if (lane == 0) lds[wv][512] = adum;
    }
    __syncthreads();
    for (int t = tid; t < KP1; t += THREADS) {
      float s = 0.f;
#pragma unroll
      for (int w2 = 0; w2 < 8; ++w2) s += lds[w2][t];
      scstore(&colp[(size_t)t * NBLK + bk], s);
    }
    gridBar();

    // ---- phase B: columns j = bk + wv*NBLK (covers all 513 for both NBLK) --
    {
      const int jcol = bk + wv * NBLK;
      if (jcol < KP1) {
        float s = 0.f;
#pragma unroll
        for (int e = 0; e < NBLK / 64; ++e)
          s += scload(&colp[(size_t)jcol * NBLK + 64 * e + lane]);
        s = waveReduceSum(s);
        if (lane == 0) {
          float bj = (jcol < KCOLS) ? powf(PB_REAL / s, FI) : (PB_DUM / s);
          scstore(&bnv[jcol], bj);
          scstore(&dcu[jcol], bj - scload(&bcv[jcol]));
        }
      }
    }
    gridBar();

    // ---- err: identical fixed-order reduction in every block ----
    if (wv == 0) {
      float s0 = 0.f;
      for (int t = lane; t < KP1; t += 64) {
        float dc = scload(&dcu[t]);
        s0 += dc * dc;
      }
      s0 = waveReduceSum(s0);
      if (lane == 0) s_err = sqrtf(s0);
    }
    __syncthreads();
    err = s_err;

    // ---- per-coordinate Aitken Delta^2 every 8 iters (guarded) ----
    // Decision is grid-uniform (it, err identical everywhere). Each b_j has a
    // single owner block/wave; stopping stays on the pure-map residual.
    if ((it & 7) == 7 && it >= 15 && err > 100.0f * STOPERR) {
      const int jcol = bk + wv * NBLK;
      if (jcol < KP1 && lane == 0) {
        float dc = scload(&dcu[jcol]);
        float dp = scload(&dpr[jcol]);
        if (fabsf(dp) > 1e-37f) {
          float rr = dc / dp;
          if (rr > -0.97f && rr < 0.95f) {
            float bx = scload(&bnv[jcol]) + (rr / (1.0f - rr)) * dc;
            if (bx > 1e-30f) scstore(&bnv[jcol], bx);  // positivity guard
          }
        }
      }
      gridBar();   // taken by ALL blocks (condition is uniform)
    }
  }

  // publish final b for the epilogue (bodies executed = it)
  if (bk == 0) {
    const float* bf = (it & 1) ? b1 : b0;
    for (int t = tid; t < KP1; t += THREADS) bfin[t] = scload(&bf[t]);
  }
}

// ---------------------------------------------------------------------------
// Kernel 3: plan = n * a * Q * b^T, recomputing Q in f32 from logits+lse
// (d_out, which held Q planes + loop scratch, is overwritten with the plan).
// ---------------------------------------------------------------------------
__global__ __launch_bounds__(1024) void plan_epilogue(
    const float* __restrict__ logits, const float* __restrict__ ws,
    float* __restrict__ out) {
  const float* lse  = ws + OFF_LSE;
  const float* a    = ws + OFF_A;
  const float* bfin = ws + OFF_BF;
  const int nw   = (gridDim.x * blockDim.x) >> 6;
  const int gw   = (blockIdx.x * blockDim.x + threadIdx.x) >> 6;
  const int lane = threadIdx.x & 63;

  const float4* b4 = reinterpret_cast<const float4*>(bfin);
  float4 rb0 = b4[lane];        // b[4l..4l+3]
  float4 rb1 = b4[64 + lane];   // b[256+4l..256+4l+3]

  for (int r = gw; r < NROWS; r += nw) {
    const float4* row4 = reinterpret_cast<const float4*>(logits + (size_t)r * KCOLS);
    float4*       out4 = reinterpret_cast<float4*>(out + (size_t)r * KCOLS);
    float L  = lse[r];
    float na = a[r] * (float)NROWS;   // n * a_i
    float4 x0 = row4[lane];
    float4 x1 = row4[64 + lane];
    float4 o0, o1;
    o0.x = na * exp2f((x0.x - L) * CQ) * rb0.x;
    o0.y = na * exp2f((x0.y - L) * CQ) * rb0.y;
    o0.z = na * exp2f((x0.z - L) * CQ) * rb0.z;
    o0.w = na * exp2f((x0.w - L) * CQ) * rb0.w;
    o1.x = na * exp2f((x1.x - L) * CQ) * rb1.x;
    o1.y = na * exp2f((x1.y - L) * CQ) * rb1.y;
    o1.z = na * exp2f((x1.z - L) * CQ) * rb1.z;
    o1.w = na * exp2f((x1.w - L) * CQ) * rb1.w;
    out4[lane]      = o0;
    out4[64 + lane] = o1;
  }
}

extern "C" void kernel_launch(void* const* d_in, const int* in_sizes, int n_in,
                              void* d_out, int out_size, void* d_ws, size_t ws_size,
                              hipStream_t stream) {
  (void)in_sizes; (void)n_in; (void)out_size; (void)ws_size;
  const float*    logits = (const float*)d_in[0];
  float*          out    = (float*)d_out;
  float*          ws     = (float*)d_ws;    // needs ~1.06 MB (proven safe)
  unsigned short* qhi    = (unsigned short*)d_out;                    // 128 MiB
  unsigned char*  qlo    = (unsigned char*)d_out + QLO_BYTE_OFF;      //  64 MiB
  float*          colp   = (float*)((char*)d_out + COLP_BYTE_OFF);    // <=1.1 MiB
  unsigned*       bar    = (unsigned*)((char*)d_out + BAR_BYTE_OFF);  // 132 B

  hipLaunchKernelGGL(lse_q_init_kernel, dim3(1024), dim3(1024), 0, stream,
                     logits, ws, qhi, qlo, bar);

  const unsigned short* qhArg = qhi;
  const unsigned char*  qlArg = qlo;
  float*                wsArg = ws;
  float*                cpArg = colp;
  unsigned*             brArg = bar;
  void* args[] = { (void*)&qhArg, (void*)&qlArg, (void*)&wsArg,
                   (void*)&cpArg, (void*)&brArg };

  // Pick grid size by the runtime's own occupancy calculator (host-side,
  // capture-safe, deterministic): 512 blocks iff 2 blocks/CU fit.
  void (*k512)(const unsigned short*, const unsigned char*, float*, float*,
               unsigned*) = sinkhorn_loop<512>;
  void (*k256)(const unsigned short*, const unsigned char*, float*, float*,
               unsigned*) = sinkhorn_loop<256>;
  int nbPerCU = 0;
  (void)hipOccupancyMaxActiveBlocksPerMultiprocessor(&nbPerCU, (const void*)k512,
                                                     THREADS, 0);
  if (nbPerCU >= 2) {
    hipLaunchCooperativeKernel((void*)k512, dim3(512), dim3(THREADS),
                               args, 0, stream);
  } else {
    hipLaunchCooperativeKernel((void*)k256, dim3(256), dim3(THREADS),
                               args, 0, stream);
  }

  hipLaunchKernelGGL(plan_epilogue, dim3(2048), dim3(1024), 0, stream,
                     logits, ws, out);
}

// Round 10
// 19360.629 us; speedup vs baseline: 1.9925x; 1.9925x over previous
//
#include <hip/hip_runtime.h>
#include <hip/hip_cooperative_groups.h>

// Problem constants (fixed by setup_inputs / reference)
constexpr int   NROWS   = 131072;
constexpr int   KCOLS   = 512;
constexpr int   KP1     = 513;   // + dummy column
constexpr float PA      = 1.0f / 131072.0f;
constexpr float PB_REAL = 0.5f / 512.0f;
constexpr float PB_DUM  = 0.5f;
constexpr float FI      = (float)(1.0 / 1.1); // GAMMA/(GAMMA+EPSILON)
constexpr float STOPERR = 1e-6f;
constexpr int   MAXIT   = 1000;
constexpr float LOG2E   = 1.4426950408889634f;
constexpr float CQ      = 10.0f * LOG2E;      // (1/EPSILON)*log2(e)
constexpr float LN2     = 0.6931471805599453f;

constexpr int THREADS = 1024;
constexpr int WPB     = THREADS / 64;     // 16 waves per block

// Workspace layout (floats). Total ~1.06 MB (well under proven 1.58 MB).
constexpr size_t OFF_LSE = 0;                        // [NROWS] row logsumexp
constexpr size_t OFF_A   = (size_t)NROWS;            // [NROWS] scaling a
constexpr int    KPAD    = 516;                      // LDS row stride (floats)
constexpr size_t OFF_B0  = 2 * (size_t)NROWS;        // [KPAD] b ping  (sc-only)
constexpr size_t OFF_B1  = OFF_B0 + KPAD;            // [KPAD] b pong  (sc-only)
constexpr size_t OFF_BF  = OFF_B0 + 2 * KPAD;        // [KPAD] b final (normal)
constexpr size_t OFF_EP  = OFF_B0 + 3 * KPAD;        // [KPAD] diff^2  (sc-only)

// Big scratch in the d_out tail (d_out = 256 MiB):
//   [0, 128 MiB)   qhi  ushort[NROWS*KCOLS]
//   [128, 192 MiB) qlo  uchar[NROWS*KCOLS]
//   [192 MiB, ...) colp float[KP1 * 512] transposed (<= 1.1 MB)
//   [200 MiB, ...) barrier words (cnt, gen)
constexpr size_t QLO_BYTE_OFF  = (size_t)NROWS * KCOLS * 2;   // 128 MiB
constexpr size_t COLP_BYTE_OFF = 192ull * 1024 * 1024;
constexpr size_t BAR_BYTE_OFF  = 200ull * 1024 * 1024;

__device__ __forceinline__ float waveReduceSum(float v) {
#pragma unroll
  for (int s = 32; s >= 1; s >>= 1) v += __shfl_xor(v, s);
  return v;
}
__device__ __forceinline__ float waveReduceMax(float v) {
#pragma unroll
  for (int s = 32; s >= 1; s >>= 1) v = fmaxf(v, __shfl_xor(v, s));
  return v;
}

// device-coherent (agent-scope) accessors: bypass non-coherent L2, hit LLC.
__device__ __forceinline__ float scload(const float* p) {
  return __hip_atomic_load(p, __ATOMIC_RELAXED, __HIP_MEMORY_SCOPE_AGENT);
}
__device__ __forceinline__ void scstore(float* p, float v) {
  __hip_atomic_store(p, v, __ATOMIC_RELAXED, __HIP_MEMORY_SCOPE_AGENT);
}

// reconstruct 8 f32 Q values (24-bit: hi ushort + lo byte) from packed loads
__device__ __forceinline__ void unpack8(const uint4 h, const uint2 l, float q[8]) {
  q[0] = __uint_as_float((h.x << 16)         | ((l.x << 8) & 0xff00u));
  q[1] = __uint_as_float((h.x & 0xffff0000u) | ( l.x       & 0xff00u));
  q[2] = __uint_as_float((h.y << 16)         | ((l.x >> 8) & 0xff00u));
  q[3] = __uint_as_float((h.y & 0xffff0000u) | ((l.x >> 16)& 0xff00u));
  q[4] = __uint_as_float((h.z << 16)         | ((l.y << 8) & 0xff00u));
  q[5] = __uint_as_float((h.z & 0xffff0000u) | ( l.y       & 0xff00u));
  q[6] = __uint_as_float((h.w << 16)         | ((l.y >> 8) & 0xff00u));
  q[7] = __uint_as_float((h.w & 0xffff0000u) | ((l.y >> 16)& 0xff00u));
}

// ---------------------------------------------------------------------------
// Kernel 1: per-row logsumexp + 24-bit Q planes (into d_out) + state init.
// ---------------------------------------------------------------------------
__global__ __launch_bounds__(1024) void lse_q_init_kernel(
    const float* __restrict__ logits, float* __restrict__ ws,
    unsigned short* __restrict__ qhi, unsigned char* __restrict__ qlo,
    unsigned* __restrict__ bar) {
  float* lse = ws + OFF_LSE;
  const int nw   = (gridDim.x * blockDim.x) >> 6;
  const int gw   = (blockIdx.x * blockDim.x + threadIdx.x) >> 6;
  const int lane = threadIdx.x & 63;

  for (int r = gw; r < NROWS; r += nw) {
    const float4* row4 = reinterpret_cast<const float4*>(logits + (size_t)r * KCOLS);
    float4 x0 = row4[lane];
    float4 x1 = row4[64 + lane];
    float m = fmaxf(fmaxf(fmaxf(x0.x, x0.y), fmaxf(x0.z, x0.w)),
                    fmaxf(fmaxf(x1.x, x1.y), fmaxf(x1.z, x1.w)));
    m = waveReduceMax(m);
    float s = exp2f((x0.x - m) * LOG2E) + exp2f((x0.y - m) * LOG2E)
            + exp2f((x0.z - m) * LOG2E) + exp2f((x0.w - m) * LOG2E)
            + exp2f((x1.x - m) * LOG2E) + exp2f((x1.y - m) * LOG2E)
            + exp2f((x1.z - m) * LOG2E) + exp2f((x1.w - m) * LOG2E);
    s = waveReduceSum(s);
    float L = m + log2f(s) * LN2;
    if (lane == 0) lse[r] = L;
    unsigned u[8];
    u[0] = __float_as_uint(exp2f((x0.x - L) * CQ)) + 0x80u;
    u[1] = __float_as_uint(exp2f((x0.y - L) * CQ)) + 0x80u;
    u[2] = __float_as_uint(exp2f((x0.z - L) * CQ)) + 0x80u;
    u[3] = __float_as_uint(exp2f((x0.w - L) * CQ)) + 0x80u;
    u[4] = __float_as_uint(exp2f((x1.x - L) * CQ)) + 0x80u;
    u[5] = __float_as_uint(exp2f((x1.y - L) * CQ)) + 0x80u;
    u[6] = __float_as_uint(exp2f((x1.z - L) * CQ)) + 0x80u;
    u[7] = __float_as_uint(exp2f((x1.w - L) * CQ)) + 0x80u;
    ushort4 hA, hB;  uchar4 lA, lB;
    hA.x = (unsigned short)(u[0] >> 16); lA.x = (unsigned char)(u[0] >> 8);
    hA.y = (unsigned short)(u[1] >> 16); lA.y = (unsigned char)(u[1] >> 8);
    hA.z = (unsigned short)(u[2] >> 16); lA.z = (unsigned char)(u[2] >> 8);
    hA.w = (unsigned short)(u[3] >> 16); lA.w = (unsigned char)(u[3] >> 8);
    hB.x = (unsigned short)(u[4] >> 16); lB.x = (unsigned char)(u[4] >> 8);
    hB.y = (unsigned short)(u[5] >> 16); lB.y = (unsigned char)(u[5] >> 8);
    hB.z = (unsigned short)(u[6] >> 16); lB.z = (unsigned char)(u[6] >> 8);
    hB.w = (unsigned short)(u[7] >> 16); lB.w = (unsigned char)(u[7] >> 8);
    *reinterpret_cast<ushort4*>(qhi + (size_t)r * KCOLS + 4 * lane)       = hA;
    *reinterpret_cast<ushort4*>(qhi + (size_t)r * KCOLS + 256 + 4 * lane) = hB;
    *reinterpret_cast<uchar4*>(qlo + (size_t)r * KCOLS + 4 * lane)        = lA;
    *reinterpret_cast<uchar4*>(qlo + (size_t)r * KCOLS + 256 + 4 * lane)  = lB;
  }
  if (blockIdx.x == 0 && threadIdx.x < KP1)
    ws[OFF_B0 + threadIdx.x] = 1.0f / 513.0f;
  if (blockIdx.x == 0 && threadIdx.x == 0) {
    bar[0]  = 0u;   // arrival counter (cumulative)
    bar[32] = 0u;   // generation
  }
}

// ---------------------------------------------------------------------------
// Kernel 2 (cooperative, custom barrier), templated on grid size NBLK.
// launch_bounds(1024,4): r5-PROVEN to compile the 4-row unroll at exactly
// 64 VGPR with zero spill. 8 waves/SIMD x 64 VGPR = 512 = full register file,
// so 2 blocks/CU are HW-feasible; the host picks NBLK via the occupancy
// calculator (proven capture-safe in r8). LDS 16.5 KB (two-stage combine).
// ---------------------------------------------------------------------------
template <int NBLK>
__global__ __launch_bounds__(THREADS, 4) void sinkhorn_loop(
    const unsigned short* __restrict__ qhi, const unsigned char* __restrict__ qlo,
    float* __restrict__ ws, float* __restrict__ colp, unsigned* __restrict__ bar) {
  float* a    = ws + OFF_A;
  float* b0   = ws + OFF_B0;
  float* b1   = ws + OFF_B1;
  float* bfin = ws + OFF_BF;
  float* ep   = ws + OFF_EP;
  unsigned* cnt = bar;
  unsigned* gen = bar + 32;

  __shared__ float lds[8][KPAD];   // 8*516*4 = 16,512 B
  __shared__ float s_err;
  __shared__ int   s_nbar;
  __shared__ int   s_dead;

  const int tid  = threadIdx.x;
  const int wv   = tid >> 6;
  const int lane = tid & 63;
  const int bk   = blockIdx.x;
  const int gw   = bk * WPB + wv;        // global wave id [0, NBLK*16)
  const int NWV  = NBLK * WPB;           // total waves

  if (tid == 0) { s_nbar = 0; s_dead = 0; }
  __syncthreads();

  // Grid barrier: __syncthreads drains vmcnt before s_barrier, so retired
  // agent-scope stores are LLC-visible before arrival. (Proven r5/r7/r8.)
  auto gridBar = [&]() {
    __syncthreads();
    if (tid == 0) {
      int nb = s_nbar;
      unsigned old = atomicAdd(cnt, 1u);
      if (old == (unsigned)(nb * NBLK + (NBLK - 1))) {
        atomicAdd(gen, 1u);
      } else if (!s_dead) {
        int spins = 0;
        while (__hip_atomic_load(gen, __ATOMIC_RELAXED, __HIP_MEMORY_SCOPE_AGENT)
               <= (unsigned)nb) {
          __builtin_amdgcn_s_sleep(1);
          if (++spins > (1 << 24)) { s_dead = 1; break; }  // fail-fast
        }
      }
      s_nbar = nb + 1;
    }
    __syncthreads();
  };

  float err = 1.0f;
  int it = 0;
  for (; it < MAXIT; ++it) {
    if (!(err > STOPERR)) break;   // NaN err also stops (matches JAX)

    const float* bcv = (it & 1) ? b1 : b0;
    float*       bnv = (it & 1) ? b0 : b1;

    // stage current b (written remotely last iter -> agent-scope loads)
    float rb[8];
#pragma unroll
    for (int e = 0; e < 8; ++e) rb[e] = scload(&bcv[8 * lane + e]);
    float bdum = scload(&bcv[512]);

    // ---- phase A: rows, 4-row unroll (r5-proven: 64 VGPR, no spill) ----
    float cp[8] = {0.f, 0.f, 0.f, 0.f, 0.f, 0.f, 0.f, 0.f};
    float adum = 0.f;
    for (int r = gw; r < NROWS; r += 4 * NWV) {
      const int r1 = r + NWV, r2 = r + 2 * NWV, r3 = r + 3 * NWV;
      uint4 h0 = ((const uint4*)(qhi + (size_t)r  * KCOLS))[lane];
      uint4 h1 = ((const uint4*)(qhi + (size_t)r1 * KCOLS))[lane];
      uint4 h2 = ((const uint4*)(qhi + (size_t)r2 * KCOLS))[lane];
      uint4 h3 = ((const uint4*)(qhi + (size_t)r3 * KCOLS))[lane];
      uint2 l0 = ((const uint2*)(qlo + (size_t)r  * KCOLS))[lane];
      uint2 l1 = ((const uint2*)(qlo + (size_t)r1 * KCOLS))[lane];
      uint2 l2 = ((const uint2*)(qlo + (size_t)r2 * KCOLS))[lane];
      uint2 l3 = ((const uint2*)(qlo + (size_t)r3 * KCOLS))[lane];
      float q0[8], q1[8], q2[8], q3[8];
      unpack8(h0, l0, q0);
      unpack8(h1, l1, q1);
      unpack8(h2, l2, q2);
      unpack8(h3, l3, q3);
      float d0 = 0.f, d1 = 0.f, d2 = 0.f, d3 = 0.f;
#pragma unroll
      for (int e = 0; e < 8; ++e) {
        d0 = fmaf(q0[e], rb[e], d0);
        d1 = fmaf(q1[e], rb[e], d1);
        d2 = fmaf(q2[e], rb[e], d2);
        d3 = fmaf(q3[e], rb[e], d3);
      }
#pragma unroll
      for (int s = 32; s >= 1; s >>= 1) {   // 4 interleaved butterflies
        d0 += __shfl_xor(d0, s);
        d1 += __shfl_xor(d1, s);
        d2 += __shfl_xor(d2, s);
        d3 += __shfl_xor(d3, s);
      }
      float ai0 = PA / (d0 + bdum);
      float ai1 = PA / (d1 + bdum);
      float ai2 = PA / (d2 + bdum);
      float ai3 = PA / (d3 + bdum);
      if (lane == 0) { a[r] = ai0; a[r1] = ai1; a[r2] = ai2; a[r3] = ai3; }
#pragma unroll
      for (int e = 0; e < 8; ++e) {
        cp[e] = fmaf(ai0, q0[e], cp[e]);
        cp[e] = fmaf(ai1, q1[e], cp[e]);
        cp[e] = fmaf(ai2, q2[e], cp[e]);
        cp[e] = fmaf(ai3, q3[e], cp[e]);
      }
      adum += (ai0 + ai1) + (ai2 + ai3);
    }
    // ---- two-stage wave combine in 8 LDS rows (16.5 KB) ----
    if (wv >= 8) {
#pragma unroll
      for (int e = 0; e < 8; ++e) lds[wv - 8][8 * lane + e] = cp[e];
      if (lane == 0) lds[wv - 8][512] = adum;
    }
    __syncthreads();
    if (wv < 8) {
#pragma unroll
      for (int e = 0; e < 8; ++e) cp[e] += lds[wv][8 * lane + e];
      if (lane == 0) adum += lds[wv][512];
    }
    __syncthreads();
    if (wv < 8) {
#pragma unroll
      for (int e = 0; e < 8; ++e) lds[wv][8 * lane + e] = cp[e];
      if (lane == 0) lds[wv][512] = adum;
    }
    __syncthreads();
    for (int t = tid; t < KP1; t += THREADS) {
      float s = 0.f;
#pragma unroll
      for (int w2 = 0; w2 < 8; ++w2) s += lds[w2][t];
      scstore(&colp[(size_t)t * NBLK + bk], s);
    }
    gridBar();

    // ---- phase B: columns j = bk + wv*NBLK (covers all 513 cols) ----
    {
      const int jcol = bk + wv * NBLK;
      if (jcol < KP1) {
        float s = 0.f;
#pragma unroll
        for (int e = 0; e < NBLK / 64; ++e)
          s += scload(&colp[(size_t)jcol * NBLK + 64 * e + lane]);
        s = waveReduceSum(s);
        if (lane == 0) {
          float bj = (jcol < KCOLS) ? powf(PB_REAL / s, FI) : (PB_DUM / s);
          scstore(&bnv[jcol], bj);
          float d = bj - scload(&bcv[jcol]);
          scstore(&ep[jcol], d * d);
        }
      }
    }
    gridBar();

    // ---- err: identical fixed-order reduction in every block ----
    if (wv == 0) {
      float s0 = 0.f;
      for (int t = lane; t < KP1; t += 64) s0 += scload(&ep[t]);
      s0 = waveReduceSum(s0);
      if (lane == 0) s_err = sqrtf(s0);
    }
    __syncthreads();
    err = s_err;
  }

  // publish final b for the epilogue (bodies executed = it)
  if (bk == 0) {
    const float* bf = (it & 1) ? b1 : b0;
    for (int t = tid; t < KP1; t += THREADS) bfin[t] = scload(&bf[t]);
  }
}

// ---------------------------------------------------------------------------
// Kernel 3: plan = n * a * Q * b^T, recomputing Q in f32 from logits+lse
// (d_out, which held Q planes + loop scratch, is overwritten with the plan).
// ---------------------------------------------------------------------------
__global__ __launch_bounds__(1024) void plan_epilogue(
    const float* __restrict__ logits, const float* __restrict__ ws,
    float* __restrict__ out) {
  const float* lse  = ws + OFF_LSE;
  const float* a    = ws + OFF_A;
  const float* bfin = ws + OFF_BF;
  const int nw   = (gridDim.x * blockDim.x) >> 6;
  const int gw   = (blockIdx.x * blockDim.x + threadIdx.x) >> 6;
  const int lane = threadIdx.x & 63;

  const float4* b4 = reinterpret_cast<const float4*>(bfin);
  float4 rb0 = b4[lane];        // b[4l..4l+3]
  float4 rb1 = b4[64 + lane];   // b[256+4l..256+4l+3]

  for (int r = gw; r < NROWS; r += nw) {
    const float4* row4 = reinterpret_cast<const float4*>(logits + (size_t)r * KCOLS);
    float4*       out4 = reinterpret_cast<float4*>(out + (size_t)r * KCOLS);
    float L  = lse[r];
    float na = a[r] * (float)NROWS;   // n * a_i
    float4 x0 = row4[lane];
    float4 x1 = row4[64 + lane];
    float4 o0, o1;
    o0.x = na * exp2f((x0.x - L) * CQ) * rb0.x;
    o0.y = na * exp2f((x0.y - L) * CQ) * rb0.y;
    o0.z = na * exp2f((x0.z - L) * CQ) * rb0.z;
    o0.w = na * exp2f((x0.w - L) * CQ) * rb0.w;
    o1.x = na * exp2f((x1.x - L) * CQ) * rb1.x;
    o1.y = na * exp2f((x1.y - L) * CQ) * rb1.y;
    o1.z = na * exp2f((x1.z - L) * CQ) * rb1.z;
    o1.w = na * exp2f((x1.w - L) * CQ) * rb1.w;
    out4[lane]      = o0;
    out4[64 + lane] = o1;
  }
}

extern "C" void kernel_launch(void* const* d_in, const int* in_sizes, int n_in,
                              void* d_out, int out_size, void* d_ws, size_t ws_size,
                              hipStream_t stream) {
  (void)in_sizes; (void)n_in; (void)out_size; (void)ws_size;
  const float*    logits = (const float*)d_in[0];
  float*          out    = (float*)d_out;
  float*          ws     = (float*)d_ws;    // needs ~1.06 MB (proven safe)
  unsigned short* qhi    = (unsigned short*)d_out;                    // 128 MiB
  unsigned char*  qlo    = (unsigned char*)d_out + QLO_BYTE_OFF;      //  64 MiB
  float*          colp   = (float*)((char*)d_out + COLP_BYTE_OFF);    // <=1.1 MiB
  unsigned*       bar    = (unsigned*)((char*)d_out + BAR_BYTE_OFF);  // 132 B

  hipLaunchKernelGGL(lse_q_init_kernel, dim3(1024), dim3(1024), 0, stream,
                     logits, ws, qhi, qlo, bar);

  const unsigned short* qhArg = qhi;
  const unsigned char*  qlArg = qlo;
  float*                wsArg = ws;
  float*                cpArg = colp;
  unsigned*             brArg = bar;
  void* args[] = { (void*)&qhArg, (void*)&qlArg, (void*)&wsArg,
                   (void*)&cpArg, (void*)&brArg };

  // Pick grid size via the runtime occupancy calculator (host-side,
  // capture-safe, deterministic): 512 blocks iff 2 blocks/CU fit at the
  // ACTUAL register count (expected 64 VGPR -> exactly 8 waves/SIMD).
  void (*k512)(const unsigned short*, const unsigned char*, float*, float*,
               unsigned*) = sinkhorn_loop<512>;
  void (*k256)(const unsigned short*, const unsigned char*, float*, float*,
               unsigned*) = sinkhorn_loop<256>;
  int nbPerCU = 0;
  (void)hipOccupancyMaxActiveBlocksPerMultiprocessor(&nbPerCU, (const void*)k512,
                                                     THREADS, 0);
  if (nbPerCU >= 2) {
    hipLaunchCooperativeKernel((void*)k512, dim3(512), dim3(THREADS),
                               args, 0, stream);
  } else {
    hipLaunchCooperativeKernel((void*)k256, dim3(256), dim3(THREADS),
                               args, 0, stream);
  }

  hipLaunchKernelGGL(plan_epilogue, dim3(2048), dim3(1024), 0, stream,
                     logits, ws, out);
}

// Round 13
// 17783.553 us; speedup vs baseline: 2.1692x; 1.0887x over previous
//
#include <hip/hip_runtime.h>

// Problem constants (fixed by setup_inputs / reference)
constexpr int   NROWS   = 131072;
constexpr int   KCOLS   = 512;
constexpr int   KP1     = 513;   // + dummy column
constexpr float PA      = 1.0f / 131072.0f;
constexpr float PB_REAL = 0.5f / 512.0f;
constexpr float PB_DUM  = 0.5f;
constexpr float FI      = (float)(1.0 / 1.1); // GAMMA/(GAMMA+EPSILON)
constexpr float STOPERR = 1e-6f;
constexpr int   MAXIT   = 1000;
constexpr float LOG2E   = 1.4426950408889634f;
constexpr float CQ      = 10.0f * LOG2E;      // (1/EPSILON)*log2(e)
constexpr float LN2     = 0.6931471805599453f;

// Proven cooperative config: 256 blocks x 1024 threads, 1 block/CU.
constexpr int BLOCKS  = 256;
constexpr int THREADS = 1024;
constexpr int WPB     = 16;                  // waves per block
constexpr int NWV     = BLOCKS * WPB;        // 4096 waves
constexpr int RPW     = NROWS / NWV;         // 32 rows per wave
constexpr int NP      = RPW / 2;             // 16 row-pairs per wave

// Streaming ring: DP row-PAIRS in flight via 16B global_load_lds (identity
// copy of a contiguous pair block; 16B width is the m97 HW-verified one).
constexpr int DP     = 3;                    // pairs in flight
constexpr int ROWB   = 1536;                 // 512 cols x 3 B
constexpr int PAIRB  = 2 * ROWB;             // 3072 B = 3 glds16 chunks
constexpr int RING_B = DP * PAIRB;           // 9216 B per wave
constexpr size_t LDS_RING  = (size_t)WPB * RING_B;        // 147456
constexpr size_t LDS_TOTAL = LDS_RING + WPB * RPW * 4;    // + a_lds = 149504

// Workspace layout (floats), ~1.06 MB (proven safe).
constexpr size_t OFF_LSE = 0;                        // [NROWS] row logsumexp
constexpr size_t OFF_A   = (size_t)NROWS;            // [NROWS] scaling a
constexpr int    KPAD    = 520;
constexpr size_t OFF_B0  = 2 * (size_t)NROWS;        // [KPAD] b ping  (sc-only)
constexpr size_t OFF_B1  = OFF_B0 + KPAD;            // [KPAD] b pong  (sc-only)
constexpr size_t OFF_BF  = OFF_B0 + 2 * KPAD;        // [KPAD] b final
constexpr size_t OFF_EP  = OFF_B0 + 3 * KPAD;        // [KPAD] diff^2  (sc-only)

// d_out tail (d_out = 256 MiB): q24 = [0, 192 MiB) (wave-permuted rows);
// colp at 192 MiB; barrier words at 200 MiB.
constexpr size_t COLP_BYTE_OFF = 192ull * 1024 * 1024;
constexpr size_t BAR_BYTE_OFF  = 200ull * 1024 * 1024;

#define WAITVM(N) do { asm volatile("s_waitcnt vmcnt(" #N ")" ::: "memory"); \
                       __builtin_amdgcn_sched_barrier(0); } while (0)
// HW fence: ds_reads retired into VGPRs before any later LDS-writing DMA.
#define WAITLG() do { asm volatile("s_waitcnt lgkmcnt(0)" ::: "memory"); \
                      __builtin_amdgcn_sched_barrier(0); } while (0)

__device__ __forceinline__ void glds16(const void* g, void* l) {
  __builtin_amdgcn_global_load_lds(
      (const __attribute__((address_space(1))) void*)g,
      (__attribute__((address_space(3))) void*)l, 16, 0, 0);
}

__device__ __forceinline__ float waveReduceSum(float v) {
#pragma unroll
  for (int s = 32; s >= 1; s >>= 1) v += __shfl_xor(v, s);
  return v;
}
__device__ __forceinline__ float waveReduceMax(float v) {
#pragma unroll
  for (int s = 32; s >= 1; s >>= 1) v = fmaxf(v, __shfl_xor(v, s));
  return v;
}

// device-coherent (agent-scope) accessors: bypass non-coherent L2, hit LLC.
__device__ __forceinline__ float scload(const float* p) {
  return __hip_atomic_load(p, __ATOMIC_RELAXED, __HIP_MEMORY_SCOPE_AGENT);
}
__device__ __forceinline__ void scstore(float* p, float v) {
  __hip_atomic_store(p, v, __ATOMIC_RELAXED, __HIP_MEMORY_SCOPE_AGENT);
}

// 4 x 24-bit values (top 24 bits of +0x80-rounded f32) packed into 3 dwords.
__device__ __forceinline__ void pack_chunk(const unsigned u[4], unsigned w[3]) {
  w[0] = u[0] | (u[1] << 24);
  w[1] = (u[1] >> 8) | (u[2] << 16);
  w[2] = (u[2] >> 16) | (u[3] << 8);
}
__device__ __forceinline__ void unpack_chunk(const unsigned* p, float q[4]) {
  unsigned a0 = p[0], a1 = p[1], a2 = p[2];
  q[0] = __uint_as_float(a0 << 8);
  q[1] = __uint_as_float(((a0 >> 16) & 0x0000FF00u) | (a1 << 16));
  q[2] = __uint_as_float(((a1 >> 8) & 0x00FFFF00u) | (a2 << 24));
  q[3] = __uint_as_float(a2 & 0xFFFFFF00u);
}

// ---------------------------------------------------------------------------
// Kernel 1: per-row logsumexp + packed 24-bit Q (3 B/elt, natural column
// order inside each 1536B row; rows stored in PER-WAVE STREAMING ORDER:
// row r lives at ((r % 4096)*32 + r/4096) * 1536, so each consumer wave's
// 32 rows are one contiguous 48 KB block) + loop-state init.
// ---------------------------------------------------------------------------
__global__ __launch_bounds__(1024) void lse_q_init_kernel(
    const float* __restrict__ logits, float* __restrict__ ws,
    unsigned char* __restrict__ q24, unsigned* __restrict__ bar) {
  float* lse = ws + OFF_LSE;
  const int nw   = (gridDim.x * blockDim.x) >> 6;
  const int gw   = (blockIdx.x * blockDim.x + threadIdx.x) >> 6;
  const int lane = threadIdx.x & 63;

  for (int r = gw; r < NROWS; r += nw) {
    const float4* row4 = reinterpret_cast<const float4*>(logits + (size_t)r * KCOLS);
    float4 x0 = row4[lane];
    float4 x1 = row4[64 + lane];
    float m = fmaxf(fmaxf(fmaxf(x0.x, x0.y), fmaxf(x0.z, x0.w)),
                    fmaxf(fmaxf(x1.x, x1.y), fmaxf(x1.z, x1.w)));
    m = waveReduceMax(m);
    float s = exp2f((x0.x - m) * LOG2E) + exp2f((x0.y - m) * LOG2E)
            + exp2f((x0.z - m) * LOG2E) + exp2f((x0.w - m) * LOG2E)
            + exp2f((x1.x - m) * LOG2E) + exp2f((x1.y - m) * LOG2E)
            + exp2f((x1.z - m) * LOG2E) + exp2f((x1.w - m) * LOG2E);
    s = waveReduceSum(s);
    float L = m + log2f(s) * LN2;
    if (lane == 0) lse[r] = L;
    unsigned uA[4], uB[4];
    uA[0] = (__float_as_uint(exp2f((x0.x - L) * CQ)) + 0x80u) >> 8;
    uA[1] = (__float_as_uint(exp2f((x0.y - L) * CQ)) + 0x80u) >> 8;
    uA[2] = (__float_as_uint(exp2f((x0.z - L) * CQ)) + 0x80u) >> 8;
    uA[3] = (__float_as_uint(exp2f((x0.w - L) * CQ)) + 0x80u) >> 8;
    uB[0] = (__float_as_uint(exp2f((x1.x - L) * CQ)) + 0x80u) >> 8;
    uB[1] = (__float_as_uint(exp2f((x1.y - L) * CQ)) + 0x80u) >> 8;
    uB[2] = (__float_as_uint(exp2f((x1.z - L) * CQ)) + 0x80u) >> 8;
    uB[3] = (__float_as_uint(exp2f((x1.w - L) * CQ)) + 0x80u) >> 8;
    unsigned wA[3], wB[3];
    pack_chunk(uA, wA);
    pack_chunk(uB, wB);
    // wave-permuted row offset: consumer wave (r % NWV), slot (r / NWV)
    size_t ro = ((size_t)(r & (NWV - 1)) * RPW + (size_t)(r >> 12)) * ROWB;
    unsigned* pA = (unsigned*)(q24 + ro + 12 * lane);        // cols 4l..4l+3
    unsigned* pB = (unsigned*)(q24 + ro + 768 + 12 * lane);  // cols 256+4l..
    pA[0] = wA[0]; pA[1] = wA[1]; pA[2] = wA[2];
    pB[0] = wB[0]; pB[1] = wB[1]; pB[2] = wB[2];
  }
  if (blockIdx.x == 0 && threadIdx.x < KP1)
    ws[OFF_B0 + threadIdx.x] = 1.0f / 513.0f;
  if (blockIdx.x == 0 && threadIdx.x == 0) {
    bar[0]  = 0u;   // arrival counter (cumulative)
    bar[32] = 0u;   // generation
  }
}

// ---------------------------------------------------------------------------
// Kernel 2 (cooperative, custom barrier): Sinkhorn loop with a 3-pair-deep
// glds16 ring per wave. Each pair block (3072 B) is an IDENTITY copy into
// LDS. Counted vmcnt waits (6 steady / 3,0 tail). RACE FIX vs r12: an
// lgkmcnt(0) HW fence between the unpack ds_reads and the same-slot refill
// DMA — ds_read completion (lgkmcnt) and global_load_lds LDS-write (vmcnt)
// are NOT mutually ordered, so without the fence a fast L2-warm DMA could
// overwrite the slot before the reads sampled it (r12 tripwire divergence).
// ---------------------------------------------------------------------------
extern __shared__ char smem[];

__global__ __launch_bounds__(THREADS) void sinkhorn_loop(
    const unsigned char* __restrict__ q24, float* __restrict__ ws,
    float* __restrict__ colp, unsigned* __restrict__ bar) {
  float* a    = ws + OFF_A;
  float* b0   = ws + OFF_B0;
  float* b1   = ws + OFF_B1;
  float* bfin = ws + OFF_BF;
  float* ep   = ws + OFF_EP;
  unsigned* cnt = bar;
  unsigned* gen = bar + 32;

  __shared__ float s_err;
  __shared__ int   s_nbar;
  __shared__ int   s_dead;

  const int tid  = threadIdx.x;
  const int wv   = tid >> 6;
  const int lane = tid & 63;
  const int bk   = blockIdx.x;
  const int gw   = bk * WPB + wv;   // global wave id [0, 4096)

  char*  ring  = smem + wv * RING_B;
  float* a_lds = (float*)(smem + LDS_RING) + wv * RPW;
  float (*lds2)[KPAD] = (float(*)[KPAD])smem;   // combine overlay (33 KB)

  const char* gwave = (const char*)q24 + (size_t)gw * RPW * ROWB;  // 48 KB block

  if (tid == 0) { s_nbar = 0; s_dead = 0; }
  __syncthreads();

  // Grid barrier (proven r5/r7/r10): __syncthreads drains vmcnt before
  // s_barrier, so retired agent-scope stores are LLC-visible on arrival.
  auto gridBar = [&]() {
    __syncthreads();
    if (tid == 0) {
      int nb = s_nbar;
      unsigned old = atomicAdd(cnt, 1u);
      if (old == (unsigned)(nb * BLOCKS + (BLOCKS - 1))) {
        atomicAdd(gen, 1u);
      } else if (!s_dead) {
        int spins = 0;
        while (__hip_atomic_load(gen, __ATOMIC_RELAXED, __HIP_MEMORY_SCOPE_AGENT)
               <= (unsigned)nb) {
          __builtin_amdgcn_s_sleep(1);
          if (++spins > (1 << 24)) { s_dead = 1; break; }  // fail-fast
        }
      }
      s_nbar = nb + 1;
    }
    __syncthreads();
  };

  float err = 1.0f;
  int it = 0;
  for (; it < MAXIT; ++it) {
    if (!(err > STOPERR)) break;   // NaN err also stops (matches JAX)

    const float* bcv = (it & 1) ? b1 : b0;
    float*       bnv = (it & 1) ? b0 : b1;

    // stage current b: lane l holds b[8l..8l+7] + dummy b[512]
    float rb[8];
#pragma unroll
    for (int e = 0; e < 8; ++e) rb[e] = scload(&bcv[8 * lane + e]);
    float bdum = scload(&bcv[512]);

    // ---- phase A: ring prologue (pairs 0..DP-1, identity copies) ----
#pragma unroll
    for (int s = 0; s < DP; ++s) {
      const char* g = gwave + (size_t)s * PAIRB;
      char* lsl = ring + s * PAIRB;
      glds16(g + 16 * lane,        lsl);
      glds16(g + 1024 + 16 * lane, lsl + 1024);
      glds16(g + 2048 + 16 * lane, lsl + 2048);
    }

    float cp[8] = {0.f, 0.f, 0.f, 0.f, 0.f, 0.f, 0.f, 0.f};
    float adum = 0.f;
    int so = 0;
#pragma unroll 1
    for (int p = 0; p < NP; ++p) {
      // wait for the oldest pair (counted, never 0 until the tail)
      if (p <= NP - 3)      WAITVM(6);
      else if (p == NP - 2) WAITVM(3);
      else                  WAITVM(0);

      const char* sl = ring + so * PAIRB;
      const unsigned* p0 = (const unsigned*)(sl + 24 * lane);         // row 2p
      const unsigned* p1 = (const unsigned*)(sl + ROWB + 24 * lane);  // row 2p+1
      float q0[8], q1[8];
      unpack_chunk(p0,     q0);
      unpack_chunk(p0 + 3, q0 + 4);
      unpack_chunk(p1,     q1);
      unpack_chunk(p1 + 3, q1 + 4);
      WAITLG();   // HW fence: reads retired before same-slot refill DMA

      // refill this slot with pair p+DP (fire-and-forget)
      if (p + DP < NP) {
        const char* g = gwave + (size_t)(p + DP) * PAIRB;
        char* lsl = ring + so * PAIRB;
        glds16(g + 16 * lane,        lsl);
        glds16(g + 1024 + 16 * lane, lsl + 1024);
        glds16(g + 2048 + 16 * lane, lsl + 2048);
      }

      float d0 = 0.f, d1 = 0.f;
#pragma unroll
      for (int e = 0; e < 8; ++e) {
        d0 = fmaf(q0[e], rb[e], d0);
        d1 = fmaf(q1[e], rb[e], d1);
      }
#pragma unroll
      for (int s = 32; s >= 1; s >>= 1) {   // 2 interleaved butterflies
        d0 += __shfl_xor(d0, s);
        d1 += __shfl_xor(d1, s);
      }
      float ai0 = PA / (d0 + bdum);
      float ai1 = PA / (d1 + bdum);
      if (lane == 0) { a_lds[2 * p] = ai0; a_lds[2 * p + 1] = ai1; }
#pragma unroll
      for (int e = 0; e < 8; ++e) {
        cp[e] = fmaf(ai0, q0[e], cp[e]);
        cp[e] = fmaf(ai1, q1[e], cp[e]);
      }
      adum += ai0 + ai1;
      so = (so == DP - 1) ? 0 : so + 1;
    }

    // bulk a-write: one store per lane (rows gw + k*NWV, k = lane)
    if (lane < RPW) a[gw + lane * NWV] = a_lds[lane];
    __syncthreads();   // all waves past WAITVM(0): ring dead, reuse as lds2

    // ---- combine 16 waves' partials in the ring LDS (overlay) ----
#pragma unroll
    for (int e = 0; e < 8; ++e) lds2[wv][8 * lane + e] = cp[e];
    if (lane == 0) lds2[wv][512] = adum;
    __syncthreads();
    for (int t = tid; t < KP1; t += THREADS) {
      float s = 0.f;
#pragma unroll
      for (int w2 = 0; w2 < WPB; ++w2) s += lds2[w2][t];
      scstore(&colp[(size_t)t * BLOCKS + bk], s);
    }
    gridBar();

    // ---- phase B: columns j = bk + wv*256 (wv<2, + col 512 on blk0/wv2) ----
    {
      const int jcol = bk + wv * BLOCKS;
      if (jcol < KP1) {
        float s = 0.f;
#pragma unroll
        for (int e = 0; e < BLOCKS / 64; ++e)
          s += scload(&colp[(size_t)jcol * BLOCKS + 64 * e + lane]);
        s = waveReduceSum(s);
        if (lane == 0) {
          float bj = (jcol < KCOLS) ? powf(PB_REAL / s, FI) : (PB_DUM / s);
          scstore(&bnv[jcol], bj);
          float d = bj - scload(&bcv[jcol]);
          scstore(&ep[jcol], d * d);
        }
      }
    }
    gridBar();

    // ---- err: identical fixed-order reduction in every block ----
    if (wv == 0) {
      float s0 = 0.f;
      for (int t = lane; t < KP1; t += 64) s0 += scload(&ep[t]);
      s0 = waveReduceSum(s0);
      if (lane == 0) s_err = sqrtf(s0);
    }
    __syncthreads();
    err = s_err;
  }

  // publish final b for the epilogue (bodies executed = it)
  if (bk == 0) {
    const float* bf = (it & 1) ? b1 : b0;
    for (int t = tid; t < KP1; t += THREADS) bfin[t] = scload(&bf[t]);
  }
}

// ---------------------------------------------------------------------------
// Kernel 3: plan = n * a * Q * b^T, recomputing Q in f32 from logits+lse
// (d_out, which held the packed Q + loop scratch, is overwritten).
// ---------------------------------------------------------------------------
__global__ __launch_bounds__(1024) void plan_epilogue(
    const float* __restrict__ logits, const float* __restrict__ ws,
    float* __restrict__ out) {
  const float* lse  = ws + OFF_LSE;
  const float* a    = ws + OFF_A;
  const float* bfin = ws + OFF_BF;
  const int nw   = (gridDim.x * blockDim.x) >> 6;
  const int gw   = (blockIdx.x * blockDim.x + threadIdx.x) >> 6;
  const int lane = threadIdx.x & 63;

  const float4* b4 = reinterpret_cast<const float4*>(bfin);
  float4 rb0 = b4[lane];        // b[4l..4l+3]
  float4 rb1 = b4[64 + lane];   // b[256+4l..256+4l+3]

  for (int r = gw; r < NROWS; r += nw) {
    const float4* row4 = reinterpret_cast<const float4*>(logits + (size_t)r * KCOLS);
    float4*       out4 = reinterpret_cast<float4*>(out + (size_t)r * KCOLS);
    float L  = lse[r];
    float na = a[r] * (float)NROWS;   // n * a_i
    float4 x0 = row4[lane];
    float4 x1 = row4[64 + lane];
    float4 o0, o1;
    o0.x = na * exp2f((x0.x - L) * CQ) * rb0.x;
    o0.y = na * exp2f((x0.y - L) * CQ) * rb0.y;
    o0.z = na * exp2f((x0.z - L) * CQ) * rb0.z;
    o0.w = na * exp2f((x0.w - L) * CQ) * rb0.w;
    o1.x = na * exp2f((x1.x - L) * CQ) * rb1.x;
    o1.y = na * exp2f((x1.y - L) * CQ) * rb1.y;
    o1.z = na * exp2f((x1.z - L) * CQ) * rb1.z;
    o1.w = na * exp2f((x1.w - L) * CQ) * rb1.w;
    out4[lane]      = o0;
    out4[64 + lane] = o1;
  }
}

extern "C" void kernel_launch(void* const* d_in, const int* in_sizes, int n_in,
                              void* d_out, int out_size, void* d_ws, size_t ws_size,
                              hipStream_t stream) {
  (void)in_sizes; (void)n_in; (void)out_size; (void)ws_size;
  const float*   logits = (const float*)d_in[0];
  float*         out    = (float*)d_out;
  float*         ws     = (float*)d_ws;    // ~1.06 MB (proven safe)
  unsigned char* q24    = (unsigned char*)d_out;                     // 192 MiB
  float*         colp   = (float*)((char*)d_out + COLP_BYTE_OFF);    // 0.5 MiB
  unsigned*      bar    = (unsigned*)((char*)d_out + BAR_BYTE_OFF);  // 132 B

  hipLaunchKernelGGL(lse_q_init_kernel, dim3(1024), dim3(1024), 0, stream,
                     logits, ws, q24, bar);

  (void)hipFuncSetAttribute((const void*)sinkhorn_loop,
                            hipFuncAttributeMaxDynamicSharedMemorySize,
                            (int)LDS_TOTAL);
  const unsigned char* qArg  = q24;
  float*               wsArg = ws;
  float*               cpArg = colp;
  unsigned*            brArg = bar;
  void* args[] = { (void*)&qArg, (void*)&wsArg, (void*)&cpArg, (void*)&brArg };
  hipLaunchCooperativeKernel((void*)sinkhorn_loop, dim3(BLOCKS), dim3(THREADS),
                             args, (unsigned)LDS_TOTAL, stream);

  hipLaunchKernelGGL(plan_epilogue, dim3(2048), dim3(1024), 0, stream,
                     logits, ws, out);
}

// Round 14
// 17128.912 us; speedup vs baseline: 2.2521x; 1.0382x over previous
//
#include <hip/hip_runtime.h>

// Problem constants (fixed by setup_inputs / reference)
constexpr int   NROWS   = 131072;
constexpr int   KCOLS   = 512;
constexpr int   KP1     = 513;   // + dummy column
constexpr float PA      = 1.0f / 131072.0f;
constexpr float PB_REAL = 0.5f / 512.0f;
constexpr float PB_DUM  = 0.5f;
constexpr float FI      = (float)(1.0 / 1.1); // GAMMA/(GAMMA+EPSILON)
constexpr float STOPERR = 1e-6f;
constexpr int   MAXIT   = 1000;
constexpr float LOG2E   = 1.4426950408889634f;
constexpr float CQ      = 10.0f * LOG2E;      // (1/EPSILON)*log2(e)
constexpr float LN2     = 0.6931471805599453f;

// Proven cooperative config: 256 blocks x 1024 threads, 1 block/CU.
constexpr int BLOCKS  = 256;
constexpr int THREADS = 1024;
constexpr int WPB     = 16;                  // waves per block
constexpr int NWV     = BLOCKS * WPB;        // 4096 waves
constexpr int RPW     = NROWS / NWV;         // 32 rows per wave
constexpr int NP      = RPW / 2;             // 16 row-pairs per wave

// Streaming ring: DP row-PAIRS in flight via 16B global_load_lds (identity
// copy of a contiguous pair block; 16B width is the m97 HW-verified one).
constexpr int DP     = 3;                    // pairs in flight
constexpr int ROWB   = 1536;                 // 512 cols x 3 B
constexpr int PAIRB  = 2 * ROWB;             // 3072 B = 3 glds16 chunks
constexpr int RING_B = DP * PAIRB;           // 9216 B per wave
constexpr size_t LDS_RING  = (size_t)WPB * RING_B;        // 147456
constexpr size_t LDS_TOTAL = LDS_RING + WPB * RPW * 4;    // + a_lds = 149504

// Workspace layout (floats), ~1.06 MB (proven safe).
constexpr size_t OFF_LSE = 0;                        // [NROWS] row logsumexp
constexpr size_t OFF_A   = (size_t)NROWS;            // [NROWS] scaling a
constexpr int    KPAD    = 520;
constexpr size_t OFF_B0  = 2 * (size_t)NROWS;        // [KPAD] b ping  (sc-only)
constexpr size_t OFF_B1  = OFF_B0 + KPAD;            // [KPAD] b pong  (sc-only)
constexpr size_t OFF_BF  = OFF_B0 + 2 * KPAD;        // [KPAD] b final
constexpr size_t OFF_EP  = OFF_B0 + 3 * KPAD;        // [KPAD] diff^2  (sc-only)

// d_out tail (d_out = 256 MiB): q24 = [0, 192 MiB) (wave-permuted rows);
// colp at 192 MiB; barrier words at 200 MiB.
constexpr size_t COLP_BYTE_OFF = 192ull * 1024 * 1024;
constexpr size_t BAR_BYTE_OFF  = 200ull * 1024 * 1024;

#define WAITVM(N) do { asm volatile("s_waitcnt vmcnt(" #N ")" ::: "memory"); \
                       __builtin_amdgcn_sched_barrier(0); } while (0)
// HW fence: ds_reads retired into VGPRs before any later LDS-writing DMA.
#define WAITLG() do { asm volatile("s_waitcnt lgkmcnt(0)" ::: "memory"); \
                      __builtin_amdgcn_sched_barrier(0); } while (0)

__device__ __forceinline__ void glds16(const void* g, void* l) {
  __builtin_amdgcn_global_load_lds(
      (const __attribute__((address_space(1))) void*)g,
      (__attribute__((address_space(3))) void*)l, 16, 0, 0);
}

__device__ __forceinline__ float waveReduceSum(float v) {
#pragma unroll
  for (int s = 32; s >= 1; s >>= 1) v += __shfl_xor(v, s);
  return v;
}
__device__ __forceinline__ float waveReduceMax(float v) {
#pragma unroll
  for (int s = 32; s >= 1; s >>= 1) v = fmaxf(v, __shfl_xor(v, s));
  return v;
}

// device-coherent (agent-scope) accessors: bypass non-coherent L2, hit LLC.
__device__ __forceinline__ float scload(const float* p) {
  return __hip_atomic_load(p, __ATOMIC_RELAXED, __HIP_MEMORY_SCOPE_AGENT);
}
__device__ __forceinline__ void scstore(float* p, float v) {
  __hip_atomic_store(p, v, __ATOMIC_RELAXED, __HIP_MEMORY_SCOPE_AGENT);
}

// 4 x 24-bit values (top 24 bits of +0x80-rounded f32) packed into 3 dwords.
__device__ __forceinline__ void pack_chunk(const unsigned u[4], unsigned w[3]) {
  w[0] = u[0] | (u[1] << 24);
  w[1] = (u[1] >> 8) | (u[2] << 16);
  w[2] = (u[2] >> 16) | (u[3] << 8);
}
__device__ __forceinline__ void unpack_chunk(const unsigned* p, float q[4]) {
  unsigned a0 = p[0], a1 = p[1], a2 = p[2];
  q[0] = __uint_as_float(a0 << 8);
  q[1] = __uint_as_float(((a0 >> 16) & 0x0000FF00u) | (a1 << 16));
  q[2] = __uint_as_float(((a1 >> 8) & 0x00FFFF00u) | (a2 << 24));
  q[3] = __uint_as_float(a2 & 0xFFFFFF00u);
}

// ---------------------------------------------------------------------------
// Kernel 1: per-row logsumexp + packed 24-bit Q (3 B/elt; lane l's chunks at
// bytes 12l [cols 4l..4l+3] and 768+12l [cols 256+4l..256+4l+3]; rows stored
// in PER-WAVE STREAMING ORDER: row r at ((r % 4096)*32 + r/4096) * 1536, so
// each consumer wave's 32 rows are one contiguous 48 KB block) + state init.
// ---------------------------------------------------------------------------
__global__ __launch_bounds__(1024) void lse_q_init_kernel(
    const float* __restrict__ logits, float* __restrict__ ws,
    unsigned char* __restrict__ q24, unsigned* __restrict__ bar) {
  float* lse = ws + OFF_LSE;
  const int nw   = (gridDim.x * blockDim.x) >> 6;
  const int gw   = (blockIdx.x * blockDim.x + threadIdx.x) >> 6;
  const int lane = threadIdx.x & 63;

  for (int r = gw; r < NROWS; r += nw) {
    const float4* row4 = reinterpret_cast<const float4*>(logits + (size_t)r * KCOLS);
    float4 x0 = row4[lane];
    float4 x1 = row4[64 + lane];
    float m = fmaxf(fmaxf(fmaxf(x0.x, x0.y), fmaxf(x0.z, x0.w)),
                    fmaxf(fmaxf(x1.x, x1.y), fmaxf(x1.z, x1.w)));
    m = waveReduceMax(m);
    float s = exp2f((x0.x - m) * LOG2E) + exp2f((x0.y - m) * LOG2E)
            + exp2f((x0.z - m) * LOG2E) + exp2f((x0.w - m) * LOG2E)
            + exp2f((x1.x - m) * LOG2E) + exp2f((x1.y - m) * LOG2E)
            + exp2f((x1.z - m) * LOG2E) + exp2f((x1.w - m) * LOG2E);
    s = waveReduceSum(s);
    float L = m + log2f(s) * LN2;
    if (lane == 0) lse[r] = L;
    unsigned uA[4], uB[4];
    uA[0] = (__float_as_uint(exp2f((x0.x - L) * CQ)) + 0x80u) >> 8;
    uA[1] = (__float_as_uint(exp2f((x0.y - L) * CQ)) + 0x80u) >> 8;
    uA[2] = (__float_as_uint(exp2f((x0.z - L) * CQ)) + 0x80u) >> 8;
    uA[3] = (__float_as_uint(exp2f((x0.w - L) * CQ)) + 0x80u) >> 8;
    uB[0] = (__float_as_uint(exp2f((x1.x - L) * CQ)) + 0x80u) >> 8;
    uB[1] = (__float_as_uint(exp2f((x1.y - L) * CQ)) + 0x80u) >> 8;
    uB[2] = (__float_as_uint(exp2f((x1.z - L) * CQ)) + 0x80u) >> 8;
    uB[3] = (__float_as_uint(exp2f((x1.w - L) * CQ)) + 0x80u) >> 8;
    unsigned wA[3], wB[3];
    pack_chunk(uA, wA);
    pack_chunk(uB, wB);
    // wave-permuted row offset: consumer wave (r % NWV), slot (r / NWV)
    size_t ro = ((size_t)(r & (NWV - 1)) * RPW + (size_t)(r >> 12)) * ROWB;
    unsigned* pA = (unsigned*)(q24 + ro + 12 * lane);        // cols 4l..4l+3
    unsigned* pB = (unsigned*)(q24 + ro + 768 + 12 * lane);  // cols 256+4l..
    pA[0] = wA[0]; pA[1] = wA[1]; pA[2] = wA[2];
    pB[0] = wB[0]; pB[1] = wB[1]; pB[2] = wB[2];
  }
  if (blockIdx.x == 0 && threadIdx.x < KP1)
    ws[OFF_B0 + threadIdx.x] = 1.0f / 513.0f;
  if (blockIdx.x == 0 && threadIdx.x == 0) {
    bar[0]  = 0u;   // arrival counter (cumulative)
    bar[32] = 0u;   // generation
  }
}

// ---------------------------------------------------------------------------
// Kernel 2 (cooperative, custom barrier): Sinkhorn loop with the r13-proven
// 3-pair glds16 ring (identity copies, counted vmcnt, lgkmcnt race fence).
// BANK-CONFLICT FIX vs r13: consumer lane l reads its two 12-byte chunks at
// byte-stride 12 (12*lane and 768+12*lane) -> first-dword bank = 3l mod 32 =
// exactly 2-way aliasing = FREE (m136), instead of 24-byte stride (4-way).
// Lane col ownership: {4l..4l+3} u {256+4l..256+4l+3} (r5's proven mapping).
// ---------------------------------------------------------------------------
extern __shared__ char smem[];

__global__ __launch_bounds__(THREADS) void sinkhorn_loop(
    const unsigned char* __restrict__ q24, float* __restrict__ ws,
    float* __restrict__ colp, unsigned* __restrict__ bar) {
  float* a    = ws + OFF_A;
  float* b0   = ws + OFF_B0;
  float* b1   = ws + OFF_B1;
  float* bfin = ws + OFF_BF;
  float* ep   = ws + OFF_EP;
  unsigned* cnt = bar;
  unsigned* gen = bar + 32;

  __shared__ float s_err;
  __shared__ int   s_nbar;
  __shared__ int   s_dead;

  const int tid  = threadIdx.x;
  const int wv   = tid >> 6;
  const int lane = tid & 63;
  const int bk   = blockIdx.x;
  const int gw   = bk * WPB + wv;   // global wave id [0, 4096)

  char*  ring  = smem + wv * RING_B;
  float* a_lds = (float*)(smem + LDS_RING) + wv * RPW;
  float (*lds2)[KPAD] = (float(*)[KPAD])smem;   // combine overlay (33 KB)

  const char* gwave = (const char*)q24 + (size_t)gw * RPW * ROWB;  // 48 KB block

  if (tid == 0) { s_nbar = 0; s_dead = 0; }
  __syncthreads();

  // Grid barrier (proven r5/r7/r10/r13): __syncthreads drains vmcnt before
  // s_barrier, so retired agent-scope stores are LLC-visible on arrival.
  auto gridBar = [&]() {
    __syncthreads();
    if (tid == 0) {
      int nb = s_nbar;
      unsigned old = atomicAdd(cnt, 1u);
      if (old == (unsigned)(nb * BLOCKS + (BLOCKS - 1))) {
        atomicAdd(gen, 1u);
      } else if (!s_dead) {
        int spins = 0;
        while (__hip_atomic_load(gen, __ATOMIC_RELAXED, __HIP_MEMORY_SCOPE_AGENT)
               <= (unsigned)nb) {
          __builtin_amdgcn_s_sleep(1);
          if (++spins > (1 << 24)) { s_dead = 1; break; }  // fail-fast
        }
      }
      s_nbar = nb + 1;
    }
    __syncthreads();
  };

  float err = 1.0f;
  int it = 0;
  for (; it < MAXIT; ++it) {
    if (!(err > STOPERR)) break;   // NaN err also stops (matches JAX)

    const float* bcv = (it & 1) ? b1 : b0;
    float*       bnv = (it & 1) ? b0 : b1;

    // stage current b: lane l holds b[4l..4l+3], b[256+4l..256+4l+3], b[512]
    float rb[8];
#pragma unroll
    for (int e = 0; e < 4; ++e) {
      rb[e]     = scload(&bcv[4 * lane + e]);
      rb[4 + e] = scload(&bcv[256 + 4 * lane + e]);
    }
    float bdum = scload(&bcv[512]);

    // ---- phase A: ring prologue (pairs 0..DP-1, identity copies) ----
#pragma unroll
    for (int s = 0; s < DP; ++s) {
      const char* g = gwave + (size_t)s * PAIRB;
      char* lsl = ring + s * PAIRB;
      glds16(g + 16 * lane,        lsl);
      glds16(g + 1024 + 16 * lane, lsl + 1024);
      glds16(g + 2048 + 16 * lane, lsl + 2048);
    }

    float cp[8] = {0.f, 0.f, 0.f, 0.f, 0.f, 0.f, 0.f, 0.f};
    float adum = 0.f;
    int so = 0;
#pragma unroll 1
    for (int p = 0; p < NP; ++p) {
      // wait for the oldest pair (counted, never 0 until the tail)
      if (p <= NP - 3)      WAITVM(6);
      else if (p == NP - 2) WAITVM(3);
      else                  WAITVM(0);

      const char* sl = ring + so * PAIRB;
      float q0[8], q1[8];
      // stride-12 reads: bank = 3*lane mod 32 -> 2-way = conflict-free
      unpack_chunk((const unsigned*)(sl + 12 * lane),              q0);
      unpack_chunk((const unsigned*)(sl + 768 + 12 * lane),        q0 + 4);
      unpack_chunk((const unsigned*)(sl + ROWB + 12 * lane),       q1);
      unpack_chunk((const unsigned*)(sl + ROWB + 768 + 12 * lane), q1 + 4);
      WAITLG();   // HW fence: reads retired before same-slot refill DMA

      // refill this slot with pair p+DP (fire-and-forget)
      if (p + DP < NP) {
        const char* g = gwave + (size_t)(p + DP) * PAIRB;
        char* lsl = ring + so * PAIRB;
        glds16(g + 16 * lane,        lsl);
        glds16(g + 1024 + 16 * lane, lsl + 1024);
        glds16(g + 2048 + 16 * lane, lsl + 2048);
      }

      float d0 = 0.f, d1 = 0.f;
#pragma unroll
      for (int e = 0; e < 8; ++e) {
        d0 = fmaf(q0[e], rb[e], d0);
        d1 = fmaf(q1[e], rb[e], d1);
      }
#pragma unroll
      for (int s = 32; s >= 1; s >>= 1) {   // 2 interleaved butterflies
        d0 += __shfl_xor(d0, s);
        d1 += __shfl_xor(d1, s);
      }
      float ai0 = PA / (d0 + bdum);
      float ai1 = PA / (d1 + bdum);
      if (lane == 0) { a_lds[2 * p] = ai0; a_lds[2 * p + 1] = ai1; }
#pragma unroll
      for (int e = 0; e < 8; ++e) {
        cp[e] = fmaf(ai0, q0[e], cp[e]);
        cp[e] = fmaf(ai1, q1[e], cp[e]);
      }
      adum += ai0 + ai1;
      so = (so == DP - 1) ? 0 : so + 1;
    }

    // bulk a-write: one store per lane (rows gw + k*NWV, k = lane)
    if (lane < RPW) a[gw + lane * NWV] = a_lds[lane];
    __syncthreads();   // all waves past WAITVM(0): ring dead, reuse as lds2

    // ---- combine 16 waves' partials in the ring LDS (overlay) ----
    // cols 4l+e at [4*lane+e], cols 256+4l+e at [256+4*lane+e] (2-way free)
#pragma unroll
    for (int e = 0; e < 4; ++e) {
      lds2[wv][4 * lane + e]       = cp[e];
      lds2[wv][256 + 4 * lane + e] = cp[4 + e];
    }
    if (lane == 0) lds2[wv][512] = adum;
    __syncthreads();
    for (int t = tid; t < KP1; t += THREADS) {
      float s = 0.f;
#pragma unroll
      for (int w2 = 0; w2 < WPB; ++w2) s += lds2[w2][t];
      scstore(&colp[(size_t)t * BLOCKS + bk], s);
    }
    gridBar();

    // ---- phase B: columns j = bk + wv*256 (wv<2, + col 512 on blk0/wv2) ----
    {
      const int jcol = bk + wv * BLOCKS;
      if (jcol < KP1) {
        float s = 0.f;
#pragma unroll
        for (int e = 0; e < BLOCKS / 64; ++e)
          s += scload(&colp[(size_t)jcol * BLOCKS + 64 * e + lane]);
        s = waveReduceSum(s);
        if (lane == 0) {
          float bj = (jcol < KCOLS) ? powf(PB_REAL / s, FI) : (PB_DUM / s);
          scstore(&bnv[jcol], bj);
          float d = bj - scload(&bcv[jcol]);
          scstore(&ep[jcol], d * d);
        }
      }
    }
    gridBar();

    // ---- err: identical fixed-order reduction in every block ----
    if (wv == 0) {
      float s0 = 0.f;
      for (int t = lane; t < KP1; t += 64) s0 += scload(&ep[t]);
      s0 = waveReduceSum(s0);
      if (lane == 0) s_err = sqrtf(s0);
    }
    __syncthreads();
    err = s_err;
  }

  // publish final b for the epilogue (bodies executed = it)
  if (bk == 0) {
    const float* bf = (it & 1) ? b1 : b0;
    for (int t = tid; t < KP1; t += THREADS) bfin[t] = scload(&bf[t]);
  }
}

// ---------------------------------------------------------------------------
// Kernel 3: plan = n * a * Q * b^T, recomputing Q in f32 from logits+lse
// (d_out, which held the packed Q + loop scratch, is overwritten).
// ---------------------------------------------------------------------------
__global__ __launch_bounds__(1024) void plan_epilogue(
    const float* __restrict__ logits, const float* __restrict__ ws,
    float* __restrict__ out) {
  const float* lse  = ws + OFF_LSE;
  const float* a    = ws + OFF_A;
  const float* bfin = ws + OFF_BF;
  const int nw   = (gridDim.x * blockDim.x) >> 6;
  const int gw   = (blockIdx.x * blockDim.x + threadIdx.x) >> 6;
  const int lane = threadIdx.x & 63;

  const float4* b4 = reinterpret_cast<const float4*>(bfin);
  float4 rb0 = b4[lane];        // b[4l..4l+3]
  float4 rb1 = b4[64 + lane];   // b[256+4l..256+4l+3]

  for (int r = gw; r < NROWS; r += nw) {
    const float4* row4 = reinterpret_cast<const float4*>(logits + (size_t)r * KCOLS);
    float4*       out4 = reinterpret_cast<float4*>(out + (size_t)r * KCOLS);
    float L  = lse[r];
    float na = a[r] * (float)NROWS;   // n * a_i
    float4 x0 = row4[lane];
    float4 x1 = row4[64 + lane];
    float4 o0, o1;
    o0.x = na * exp2f((x0.x - L) * CQ) * rb0.x;
    o0.y = na * exp2f((x0.y - L) * CQ) * rb0.y;
    o0.z = na * exp2f((x0.z - L) * CQ) * rb0.z;
    o0.w = na * exp2f((x0.w - L) * CQ) * rb0.w;
    o1.x = na * exp2f((x1.x - L) * CQ) * rb1.x;
    o1.y = na * exp2f((x1.y - L) * CQ) * rb1.y;
    o1.z = na * exp2f((x1.z - L) * CQ) * rb1.z;
    o1.w = na * exp2f((x1.w - L) * CQ) * rb1.w;
    out4[lane]      = o0;
    out4[64 + lane] = o1;
  }
}

extern "C" void kernel_launch(void* const* d_in, const int* in_sizes, int n_in,
                              void* d_out, int out_size, void* d_ws, size_t ws_size,
                              hipStream_t stream) {
  (void)in_sizes; (void)n_in; (void)out_size; (void)ws_size;
  const float*   logits = (const float*)d_in[0];
  float*         out    = (float*)d_out;
  float*         ws     = (float*)d_ws;    // ~1.06 MB (proven safe)
  unsigned char* q24    = (unsigned char*)d_out;                     // 192 MiB
  float*         colp   = (float*)((char*)d_out + COLP_BYTE_OFF);    // 0.5 MiB
  unsigned*      bar    = (unsigned*)((char*)d_out + BAR_BYTE_OFF);  // 132 B

  hipLaunchKernelGGL(lse_q_init_kernel, dim3(1024), dim3(1024), 0, stream,
                     logits, ws, q24, bar);

  (void)hipFuncSetAttribute((const void*)sinkhorn_loop,
                            hipFuncAttributeMaxDynamicSharedMemorySize,
                            (int)LDS_TOTAL);
  const unsigned char* qArg  = q24;
  float*               wsArg = ws;
  float*               cpArg = colp;
  unsigned*            brArg = bar;
  void* args[] = { (void*)&qArg, (void*)&wsArg, (void*)&cpArg, (void*)&brArg };
  hipLaunchCooperativeKernel((void*)sinkhorn_loop, dim3(BLOCKS), dim3(THREADS),
                             args, (unsigned)LDS_TOTAL, stream);

  hipLaunchKernelGGL(plan_epilogue, dim3(2048), dim3(1024), 0, stream,
                     logits, ws, out);
}

// Round 15
// 17123.773 us; speedup vs baseline: 2.2528x; 1.0003x over previous
//
#include <hip/hip_runtime.h>

// Problem constants (fixed by setup_inputs / reference)
constexpr int   NROWS   = 131072;
constexpr int   KCOLS   = 512;
constexpr int   KP1     = 513;   // + dummy column
constexpr float PA      = 1.0f / 131072.0f;
constexpr float PB_REAL = 0.5f / 512.0f;
constexpr float PB_DUM  = 0.5f;
constexpr float FI      = (float)(1.0 / 1.1); // GAMMA/(GAMMA+EPSILON)
constexpr float STOPERR = 1e-6f;
constexpr int   MAXIT   = 1000;
constexpr float LOG2E   = 1.4426950408889634f;
constexpr float CQ      = 10.0f * LOG2E;      // (1/EPSILON)*log2(e)
constexpr float LN2     = 0.6931471805599453f;

// V64 (r14-proven) cooperative config: 256 blocks x 1024 threads, 1 block/CU.
constexpr int BLOCKS  = 256;
constexpr int THREADS = 1024;
constexpr int WPB     = 16;                  // waves per block
constexpr int NWV     = BLOCKS * WPB;        // 4096 waves
constexpr int RPW     = NROWS / NWV;         // 32 rows per wave
constexpr int NP      = RPW / 2;             // 16 row-pairs per wave

// V32 config: 512 blocks x 1024 threads = 2 blocks/CU (needs VGPR<=32).
constexpr int NB2     = 512;
constexpr int NWV2    = NB2 * WPB;           // 8192 waves
constexpr int RPW2    = NROWS / NWV2;        // 16 rows per wave

// Streaming ring (V64): DP row-PAIRS in flight via 16B global_load_lds.
constexpr int DP     = 3;                    // pairs in flight
constexpr int ROWB   = 1536;                 // 512 cols x 3 B
constexpr int PAIRB  = 2 * ROWB;             // 3072 B = 3 glds16 chunks
constexpr int RING_B = DP * PAIRB;           // 9216 B per wave
constexpr size_t LDS_RING  = (size_t)WPB * RING_B;        // 147456
constexpr size_t LDS_TOTAL = LDS_RING + WPB * RPW * 4;    // + a_lds = 149504

// Workspace layout (floats), ~1.06 MB (proven safe).
constexpr size_t OFF_LSE = 0;                        // [NROWS] row logsumexp
constexpr size_t OFF_A   = (size_t)NROWS;            // [NROWS] scaling a
constexpr int    KPAD    = 520;
constexpr size_t OFF_B0  = 2 * (size_t)NROWS;        // [KPAD] b ping  (sc-only)
constexpr size_t OFF_B1  = OFF_B0 + KPAD;            // [KPAD] b pong  (sc-only)
constexpr size_t OFF_BF  = OFF_B0 + 2 * KPAD;        // [KPAD] b final
constexpr size_t OFF_EP  = OFF_B0 + 3 * KPAD;        // [KPAD] diff^2  (sc-only)

// d_out tail (d_out = 256 MiB): q24 = [0, 192 MiB) (wave-permuted rows);
// colp (KP1*512 floats, serves both variants) at 192 MiB; barrier at 200 MiB.
constexpr size_t COLP_BYTE_OFF = 192ull * 1024 * 1024;
constexpr size_t BAR_BYTE_OFF  = 200ull * 1024 * 1024;

#define WAITVM(N) do { asm volatile("s_waitcnt vmcnt(" #N ")" ::: "memory"); \
                       __builtin_amdgcn_sched_barrier(0); } while (0)
#define WAITLG() do { asm volatile("s_waitcnt lgkmcnt(0)" ::: "memory"); \
                      __builtin_amdgcn_sched_barrier(0); } while (0)

__device__ __forceinline__ void glds16(const void* g, void* l) {
  __builtin_amdgcn_global_load_lds(
      (const __attribute__((address_space(1))) void*)g,
      (__attribute__((address_space(3))) void*)l, 16, 0, 0);
}

__device__ __forceinline__ float waveReduceSum(float v) {
#pragma unroll
  for (int s = 32; s >= 1; s >>= 1) v += __shfl_xor(v, s);
  return v;
}
__device__ __forceinline__ float waveReduceMax(float v) {
#pragma unroll
  for (int s = 32; s >= 1; s >>= 1) v = fmaxf(v, __shfl_xor(v, s));
  return v;
}

// device-coherent (agent-scope) accessors: bypass non-coherent L2, hit LLC.
__device__ __forceinline__ float scload(const float* p) {
  return __hip_atomic_load(p, __ATOMIC_RELAXED, __HIP_MEMORY_SCOPE_AGENT);
}
__device__ __forceinline__ void scstore(float* p, float v) {
  __hip_atomic_store(p, v, __ATOMIC_RELAXED, __HIP_MEMORY_SCOPE_AGENT);
}

// 4 x 24-bit values (top 24 bits of +0x80-rounded f32) packed into 3 dwords.
__device__ __forceinline__ void pack_chunk(const unsigned u[4], unsigned w[3]) {
  w[0] = u[0] | (u[1] << 24);
  w[1] = (u[1] >> 8) | (u[2] << 16);
  w[2] = (u[2] >> 16) | (u[3] << 8);
}
__device__ __forceinline__ void unpack_chunk(const unsigned* p, float q[4]) {
  unsigned a0 = p[0], a1 = p[1], a2 = p[2];
  q[0] = __uint_as_float(a0 << 8);
  q[1] = __uint_as_float(((a0 >> 16) & 0x0000FF00u) | (a1 << 16));
  q[2] = __uint_as_float(((a1 >> 8) & 0x00FFFF00u) | (a2 << 24));
  q[3] = __uint_as_float(a2 & 0xFFFFFF00u);
}
__device__ __forceinline__ void unpackR(unsigned a0, unsigned a1, unsigned a2,
                                        float q[4]) {
  q[0] = __uint_as_float(a0 << 8);
  q[1] = __uint_as_float(((a0 >> 16) & 0x0000FF00u) | (a1 << 16));
  q[2] = __uint_as_float(((a1 >> 8) & 0x00FFFF00u) | (a2 << 24));
  q[3] = __uint_as_float(a2 & 0xFFFFFF00u);
}

// ---------------------------------------------------------------------------
// Kernel 1: per-row logsumexp + packed 24-bit Q (3 B/elt; lane l's chunks at
// bytes 12l [cols 4l..4l+3] and 768+12l [cols 256+4l..256+4l+3]; rows stored
// in PER-WAVE STREAMING ORDER: row r at ((r % 4096)*32 + r/4096) * 1536;
// consumable by both 4096-wave (48KB/wave) and 8192-wave (24KB/wave) grids)
// + loop-state init.
// ---------------------------------------------------------------------------
__global__ __launch_bounds__(1024) void lse_q_init_kernel(
    const float* __restrict__ logits, float* __restrict__ ws,
    unsigned char* __restrict__ q24, unsigned* __restrict__ bar) {
  float* lse = ws + OFF_LSE;
  const int nw   = (gridDim.x * blockDim.x) >> 6;
  const int gw   = (blockIdx.x * blockDim.x + threadIdx.x) >> 6;
  const int lane = threadIdx.x & 63;

  for (int r = gw; r < NROWS; r += nw) {
    const float4* row4 = reinterpret_cast<const float4*>(logits + (size_t)r * KCOLS);
    float4 x0 = row4[lane];
    float4 x1 = row4[64 + lane];
    float m = fmaxf(fmaxf(fmaxf(x0.x, x0.y), fmaxf(x0.z, x0.w)),
                    fmaxf(fmaxf(x1.x, x1.y), fmaxf(x1.z, x1.w)));
    m = waveReduceMax(m);
    float s = exp2f((x0.x - m) * LOG2E) + exp2f((x0.y - m) * LOG2E)
            + exp2f((x0.z - m) * LOG2E) + exp2f((x0.w - m) * LOG2E)
            + exp2f((x1.x - m) * LOG2E) + exp2f((x1.y - m) * LOG2E)
            + exp2f((x1.z - m) * LOG2E) + exp2f((x1.w - m) * LOG2E);
    s = waveReduceSum(s);
    float L = m + log2f(s) * LN2;
    if (lane == 0) lse[r] = L;
    unsigned uA[4], uB[4];
    uA[0] = (__float_as_uint(exp2f((x0.x - L) * CQ)) + 0x80u) >> 8;
    uA[1] = (__float_as_uint(exp2f((x0.y - L) * CQ)) + 0x80u) >> 8;
    uA[2] = (__float_as_uint(exp2f((x0.z - L) * CQ)) + 0x80u) >> 8;
    uA[3] = (__float_as_uint(exp2f((x0.w - L) * CQ)) + 0x80u) >> 8;
    uB[0] = (__float_as_uint(exp2f((x1.x - L) * CQ)) + 0x80u) >> 8;
    uB[1] = (__float_as_uint(exp2f((x1.y - L) * CQ)) + 0x80u) >> 8;
    uB[2] = (__float_as_uint(exp2f((x1.z - L) * CQ)) + 0x80u) >> 8;
    uB[3] = (__float_as_uint(exp2f((x1.w - L) * CQ)) + 0x80u) >> 8;
    unsigned wA[3], wB[3];
    pack_chunk(uA, wA);
    pack_chunk(uB, wB);
    // wave-permuted row offset: consumer wave (r % 4096), slot (r / 4096)
    size_t ro = ((size_t)(r & 4095) * 32 + (size_t)(r >> 12)) * ROWB;
    unsigned* pA = (unsigned*)(q24 + ro + 12 * lane);        // cols 4l..4l+3
    unsigned* pB = (unsigned*)(q24 + ro + 768 + 12 * lane);  // cols 256+4l..
    pA[0] = wA[0]; pA[1] = wA[1]; pA[2] = wA[2];
    pB[0] = wB[0]; pB[1] = wB[1]; pB[2] = wB[2];
  }
  if (blockIdx.x == 0 && threadIdx.x < KP1)
    ws[OFF_B0 + threadIdx.x] = 1.0f / 513.0f;
  if (blockIdx.x == 0 && threadIdx.x == 0) {
    bar[0]  = 0u;   // arrival counter (cumulative)
    bar[32] = 0u;   // generation
  }
}

// ---------------------------------------------------------------------------
// Kernel 2a "V32" (cooperative, 512 blocks, 2 blocks/CU = 32 waves/CU):
// minimal-register phase A (no ring; per row: one addr pair + 6 dword loads
// with imm offsets, q[8]+rb[8]+cp[8] ~ 31 VGPR). Launched ONLY if it
// compiled spill-free at <=32 VGPR (host checks localSizeBytes==0 and
// occupancy >= 2); else the proven V64 runs. Tests waves->BW hypothesis.
// ---------------------------------------------------------------------------
__global__ __launch_bounds__(THREADS, 8) void sinkhorn_v32(
    const unsigned char* __restrict__ q24, float* __restrict__ ws,
    float* __restrict__ colp, unsigned* __restrict__ bar) {
  float* a    = ws + OFF_A;
  float* b0   = ws + OFF_B0;
  float* b1   = ws + OFF_B1;
  float* bfin = ws + OFF_BF;
  float* ep   = ws + OFF_EP;
  unsigned* cnt = bar;
  unsigned* gen = bar + 32;

  __shared__ float lds2[WPB][KPAD];   // 16*520*4 = 33,280 B
  __shared__ float s_err;
  __shared__ int   s_nbar;
  __shared__ int   s_dead;

  const int tid  = threadIdx.x;
  const int wv   = tid >> 6;
  const int lane = tid & 63;
  const int bk   = blockIdx.x;
  const int gw   = bk * WPB + wv;        // global wave id [0, 8192)
  const int v4   = gw & 4095;
  const int hi   = gw >> 12;             // 0 or 1
  // this wave's 16 rows: contiguous 24KB half-block of the permuted layout
  const unsigned char* gsv = q24 + ((size_t)v4 * 32 + (size_t)hi * 16) * ROWB;
  const int rA = v4 + hi * 65536;        // physical row of slot s: rA + s*4096

  if (tid == 0) { s_nbar = 0; s_dead = 0; }
  __syncthreads();

  auto gridBar = [&]() {
    __syncthreads();
    if (tid == 0) {
      int nb = s_nbar;
      unsigned old = atomicAdd(cnt, 1u);
      if (old == (unsigned)(nb * NB2 + (NB2 - 1))) {
        atomicAdd(gen, 1u);
      } else if (!s_dead) {
        int spins = 0;
        while (__hip_atomic_load(gen, __ATOMIC_RELAXED, __HIP_MEMORY_SCOPE_AGENT)
               <= (unsigned)nb) {
          __builtin_amdgcn_s_sleep(1);
          if (++spins > (1 << 24)) { s_dead = 1; break; }  // fail-fast
        }
      }
      s_nbar = nb + 1;
    }
    __syncthreads();
  };

  float err = 1.0f;
  int it = 0;
  for (; it < MAXIT; ++it) {
    if (!(err > STOPERR)) break;   // NaN err also stops (matches JAX)

    const float* bcv = (it & 1) ? b1 : b0;
    float*       bnv = (it & 1) ? b0 : b1;

    // stage current b: lane l holds b[4l..4l+3], b[256+4l..256+4l+3], b[512]
    float rb[8];
#pragma unroll
    for (int e = 0; e < 4; ++e) {
      rb[e]     = scload(&bcv[4 * lane + e]);
      rb[4 + e] = scload(&bcv[256 + 4 * lane + e]);
    }
    float bdum = scload(&bcv[512]);

    // ---- phase A: 16 rows, one at a time, minimal registers ----
    float cp[8] = {0.f, 0.f, 0.f, 0.f, 0.f, 0.f, 0.f, 0.f};
    float adum = 0.f;
#pragma unroll 1
    for (int s = 0; s < RPW2; ++s) {
      const unsigned* pa =
          (const unsigned*)(gsv + (size_t)s * ROWB + 12 * lane);
      unsigned c0 = pa[0], c1 = pa[1], c2 = pa[2];        // cols 4l..4l+3
      unsigned d0w = pa[192], d1w = pa[193], d2w = pa[194]; // +768B: 256+4l..
      float q[8];
      unpackR(c0, c1, c2, q);
      unpackR(d0w, d1w, d2w, q + 4);
      float d = 0.f;
#pragma unroll
      for (int e = 0; e < 8; ++e) d = fmaf(q[e], rb[e], d);
#pragma unroll
      for (int s2 = 32; s2 >= 1; s2 >>= 1) d += __shfl_xor(d, s2);
      float ai = PA / (d + bdum);
      if (lane == 0) a[rA + (s << 12)] = ai;
#pragma unroll
      for (int e = 0; e < 8; ++e) cp[e] = fmaf(ai, q[e], cp[e]);
      adum += ai;
    }

    // ---- combine 16 waves' partials (2-way-free layout) ----
#pragma unroll
    for (int e = 0; e < 4; ++e) {
      lds2[wv][4 * lane + e]       = cp[e];
      lds2[wv][256 + 4 * lane + e] = cp[4 + e];
    }
    if (lane == 0) lds2[wv][512] = adum;
    __syncthreads();
    for (int t = tid; t < KP1; t += THREADS) {
      float s = 0.f;
#pragma unroll
      for (int w2 = 0; w2 < WPB; ++w2) s += lds2[w2][t];
      scstore(&colp[(size_t)t * NB2 + bk], s);
    }
    gridBar();

    // ---- phase B: jcol = bk (+ col 512 on blk0/wv1) ----
    {
      const int jcol = bk + wv * NB2;
      if (jcol < KP1) {
        float s = 0.f;
#pragma unroll
        for (int e = 0; e < NB2 / 64; ++e)
          s += scload(&colp[(size_t)jcol * NB2 + 64 * e + lane]);
        s = waveReduceSum(s);
        if (lane == 0) {
          float bj = (jcol < KCOLS) ? powf(PB_REAL / s, FI) : (PB_DUM / s);
          scstore(&bnv[jcol], bj);
          float d = bj - scload(&bcv[jcol]);
          scstore(&ep[jcol], d * d);
        }
      }
    }
    gridBar();

    // ---- err: identical fixed-order reduction in every block ----
    if (wv == 0) {
      float s0 = 0.f;
      for (int t = lane; t < KP1; t += 64) s0 += scload(&ep[t]);
      s0 = waveReduceSum(s0);
      if (lane == 0) s_err = sqrtf(s0);
    }
    __syncthreads();
    err = s_err;
  }

  if (bk == 0) {
    const float* bf = (it & 1) ? b1 : b0;
    for (int t = tid; t < KP1; t += THREADS) bfin[t] = scload(&bf[t]);
  }
}

// ---------------------------------------------------------------------------
// Kernel 2b "V64" (r14-proven, byte-identical): 3-pair glds16 ring, counted
// vmcnt, lgkmcnt race fence, stride-12 conflict-free unpack reads.
// ---------------------------------------------------------------------------
extern __shared__ char smem[];

__global__ __launch_bounds__(THREADS) void sinkhorn_loop(
    const unsigned char* __restrict__ q24, float* __restrict__ ws,
    float* __restrict__ colp, unsigned* __restrict__ bar) {
  float* a    = ws + OFF_A;
  float* b0   = ws + OFF_B0;
  float* b1   = ws + OFF_B1;
  float* bfin = ws + OFF_BF;
  float* ep   = ws + OFF_EP;
  unsigned* cnt = bar;
  unsigned* gen = bar + 32;

  __shared__ float s_err;
  __shared__ int   s_nbar;
  __shared__ int   s_dead;

  const int tid  = threadIdx.x;
  const int wv   = tid >> 6;
  const int lane = tid & 63;
  const int bk   = blockIdx.x;
  const int gw   = bk * WPB + wv;   // global wave id [0, 4096)

  char*  ring  = smem + wv * RING_B;
  float* a_lds = (float*)(smem + LDS_RING) + wv * RPW;
  float (*lds2)[KPAD] = (float(*)[KPAD])smem;   // combine overlay (33 KB)

  const char* gwave = (const char*)q24 + (size_t)gw * RPW * ROWB;  // 48 KB block

  if (tid == 0) { s_nbar = 0; s_dead = 0; }
  __syncthreads();

  auto gridBar = [&]() {
    __syncthreads();
    if (tid == 0) {
      int nb = s_nbar;
      unsigned old = atomicAdd(cnt, 1u);
      if (old == (unsigned)(nb * BLOCKS + (BLOCKS - 1))) {
        atomicAdd(gen, 1u);
      } else if (!s_dead) {
        int spins = 0;
        while (__hip_atomic_load(gen, __ATOMIC_RELAXED, __HIP_MEMORY_SCOPE_AGENT)
               <= (unsigned)nb) {
          __builtin_amdgcn_s_sleep(1);
          if (++spins > (1 << 24)) { s_dead = 1; break; }  // fail-fast
        }
      }
      s_nbar = nb + 1;
    }
    __syncthreads();
  };

  float err = 1.0f;
  int it = 0;
  for (; it < MAXIT; ++it) {
    if (!(err > STOPERR)) break;   // NaN err also stops (matches JAX)

    const float* bcv = (it & 1) ? b1 : b0;
    float*       bnv = (it & 1) ? b0 : b1;

    float rb[8];
#pragma unroll
    for (int e = 0; e < 4; ++e) {
      rb[e]     = scload(&bcv[4 * lane + e]);
      rb[4 + e] = scload(&bcv[256 + 4 * lane + e]);
    }
    float bdum = scload(&bcv[512]);

#pragma unroll
    for (int s = 0; s < DP; ++s) {
      const char* g = gwave + (size_t)s * PAIRB;
      char* lsl = ring + s * PAIRB;
      glds16(g + 16 * lane,        lsl);
      glds16(g + 1024 + 16 * lane, lsl + 1024);
      glds16(g + 2048 + 16 * lane, lsl + 2048);
    }

    float cp[8] = {0.f, 0.f, 0.f, 0.f, 0.f, 0.f, 0.f, 0.f};
    float adum = 0.f;
    int so = 0;
#pragma unroll 1
    for (int p = 0; p < NP; ++p) {
      if (p <= NP - 3)      WAITVM(6);
      else if (p == NP - 2) WAITVM(3);
      else                  WAITVM(0);

      const char* sl = ring + so * PAIRB;
      float q0[8], q1[8];
      unpack_chunk((const unsigned*)(sl + 12 * lane),              q0);
      unpack_chunk((const unsigned*)(sl + 768 + 12 * lane),        q0 + 4);
      unpack_chunk((const unsigned*)(sl + ROWB + 12 * lane),       q1);
      unpack_chunk((const unsigned*)(sl + ROWB + 768 + 12 * lane), q1 + 4);
      WAITLG();   // HW fence: reads retired before same-slot refill DMA

      if (p + DP < NP) {
        const char* g = gwave + (size_t)(p + DP) * PAIRB;
        char* lsl = ring + so * PAIRB;
        glds16(g + 16 * lane,        lsl);
        glds16(g + 1024 + 16 * lane, lsl + 1024);
        glds16(g + 2048 + 16 * lane, lsl + 2048);
      }

      float d0 = 0.f, d1 = 0.f;
#pragma unroll
      for (int e = 0; e < 8; ++e) {
        d0 = fmaf(q0[e], rb[e], d0);
        d1 = fmaf(q1[e], rb[e], d1);
      }
#pragma unroll
      for (int s = 32; s >= 1; s >>= 1) {
        d0 += __shfl_xor(d0, s);
        d1 += __shfl_xor(d1, s);
      }
      float ai0 = PA / (d0 + bdum);
      float ai1 = PA / (d1 + bdum);
      if (lane == 0) { a_lds[2 * p] = ai0; a_lds[2 * p + 1] = ai1; }
#pragma unroll
      for (int e = 0; e < 8; ++e) {
        cp[e] = fmaf(ai0, q0[e], cp[e]);
        cp[e] = fmaf(ai1, q1[e], cp[e]);
      }
      adum += ai0 + ai1;
      so = (so == DP - 1) ? 0 : so + 1;
    }

    if (lane < RPW) a[gw + lane * NWV] = a_lds[lane];
    __syncthreads();

#pragma unroll
    for (int e = 0; e < 4; ++e) {
      lds2[wv][4 * lane + e]       = cp[e];
      lds2[wv][256 + 4 * lane + e] = cp[4 + e];
    }
    if (lane == 0) lds2[wv][512] = adum;
    __syncthreads();
    for (int t = tid; t < KP1; t += THREADS) {
      float s = 0.f;
#pragma unroll
      for (int w2 = 0; w2 < WPB; ++w2) s += lds2[w2][t];
      scstore(&colp[(size_t)t * BLOCKS + bk], s);
    }
    gridBar();

    {
      const int jcol = bk + wv * BLOCKS;
      if (jcol < KP1) {
        float s = 0.f;
#pragma unroll
        for (int e = 0; e < BLOCKS / 64; ++e)
          s += scload(&colp[(size_t)jcol * BLOCKS + 64 * e + lane]);
        s = waveReduceSum(s);
        if (lane == 0) {
          float bj = (jcol < KCOLS) ? powf(PB_REAL / s, FI) : (PB_DUM / s);
          scstore(&bnv[jcol], bj);
          float d = bj - scload(&bcv[jcol]);
          scstore(&ep[jcol], d * d);
        }
      }
    }
    gridBar();

    if (wv == 0) {
      float s0 = 0.f;
      for (int t = lane; t < KP1; t += 64) s0 += scload(&ep[t]);
      s0 = waveReduceSum(s0);
      if (lane == 0) s_err = sqrtf(s0);
    }
    __syncthreads();
    err = s_err;
  }

  if (bk == 0) {
    const float* bf = (it & 1) ? b1 : b0;
    for (int t = tid; t < KP1; t += THREADS) bfin[t] = scload(&bf[t]);
  }
}

// ---------------------------------------------------------------------------
// Kernel 3: plan = n * a * Q * b^T, recomputing Q in f32 from logits+lse
// (d_out, which held the packed Q + loop scratch, is overwritten).
// ---------------------------------------------------------------------------
__global__ __launch_bounds__(1024) void plan_epilogue(
    const float* __restrict__ logits, const float* __restrict__ ws,
    float* __restrict__ out) {
  const float* lse  = ws + OFF_LSE;
  const float* a    = ws + OFF_A;
  const float* bfin = ws + OFF_BF;
  const int nw   = (gridDim.x * blockDim.x) >> 6;
  const int gw   = (blockIdx.x * blockDim.x + threadIdx.x) >> 6;
  const int lane = threadIdx.x & 63;

  const float4* b4 = reinterpret_cast<const float4*>(bfin);
  float4 rb0 = b4[lane];        // b[4l..4l+3]
  float4 rb1 = b4[64 + lane];   // b[256+4l..256+4l+3]

  for (int r = gw; r < NROWS; r += nw) {
    const float4* row4 = reinterpret_cast<const float4*>(logits + (size_t)r * KCOLS);
    float4*       out4 = reinterpret_cast<float4*>(out + (size_t)r * KCOLS);
    float L  = lse[r];
    float na = a[r] * (float)NROWS;   // n * a_i
    float4 x0 = row4[lane];
    float4 x1 = row4[64 + lane];
    float4 o0, o1;
    o0.x = na * exp2f((x0.x - L) * CQ) * rb0.x;
    o0.y = na * exp2f((x0.y - L) * CQ) * rb0.y;
    o0.z = na * exp2f((x0.z - L) * CQ) * rb0.z;
    o0.w = na * exp2f((x0.w - L) * CQ) * rb0.w;
    o1.x = na * exp2f((x1.x - L) * CQ) * rb1.x;
    o1.y = na * exp2f((x1.y - L) * CQ) * rb1.y;
    o1.z = na * exp2f((x1.z - L) * CQ) * rb1.z;
    o1.w = na * exp2f((x1.w - L) * CQ) * rb1.w;
    out4[lane]      = o0;
    out4[64 + lane] = o1;
  }
}

extern "C" void kernel_launch(void* const* d_in, const int* in_sizes, int n_in,
                              void* d_out, int out_size, void* d_ws, size_t ws_size,
                              hipStream_t stream) {
  (void)in_sizes; (void)n_in; (void)out_size; (void)ws_size;
  const float*   logits = (const float*)d_in[0];
  float*         out    = (float*)d_out;
  float*         ws     = (float*)d_ws;    // ~1.06 MB (proven safe)
  unsigned char* q24    = (unsigned char*)d_out;                     // 192 MiB
  float*         colp   = (float*)((char*)d_out + COLP_BYTE_OFF);    // ~1 MiB
  unsigned*      bar    = (unsigned*)((char*)d_out + BAR_BYTE_OFF);  // 132 B

  hipLaunchKernelGGL(lse_q_init_kernel, dim3(1024), dim3(1024), 0, stream,
                     logits, ws, q24, bar);

  const unsigned char* qArg  = q24;
  float*               wsArg = ws;
  float*               cpArg = colp;
  unsigned*            brArg = bar;
  void* args[] = { (void*)&qArg, (void*)&wsArg, (void*)&cpArg, (void*)&brArg };

  // Select V32 (512 blocks, 32 waves/CU) ONLY if it compiled spill-free and
  // the runtime grants 2 blocks/CU. Host-side queries: deterministic,
  // capture-safe (r8/r10 precedent). Fallback = r14-proven V64.
  bool useV32 = false;
  hipFuncAttributes fa;
  if (hipFuncGetAttributes(&fa, (const void*)sinkhorn_v32) == hipSuccess &&
      fa.localSizeBytes == 0) {
    int nb = 0;
    if (hipOccupancyMaxActiveBlocksPerMultiprocessor(
            &nb, (const void*)sinkhorn_v32, THREADS, 0) == hipSuccess &&
        nb >= 2) {
      useV32 = true;
    }
  }

  if (useV32) {
    hipLaunchCooperativeKernel((void*)sinkhorn_v32, dim3(NB2), dim3(THREADS),
                               args, 0, stream);
  } else {
    (void)hipFuncSetAttribute((const void*)sinkhorn_loop,
                              hipFuncAttributeMaxDynamicSharedMemorySize,
                              (int)LDS_TOTAL);
    hipLaunchCooperativeKernel((void*)sinkhorn_loop, dim3(BLOCKS), dim3(THREADS),
                               args, (unsigned)LDS_TOTAL, stream);
  }

  hipLaunchKernelGGL(plan_epilogue, dim3(2048), dim3(1024), 0, stream,
                     logits, ws, out);
}

// Round 16
// 17108.543 us; speedup vs baseline: 2.2548x; 1.0009x over previous
//
#include <hip/hip_runtime.h>

// Problem constants (fixed by setup_inputs / reference)
constexpr int   NROWS   = 131072;
constexpr int   KCOLS   = 512;
constexpr int   KP1     = 513;   // + dummy column
constexpr float PA      = 1.0f / 131072.0f;
constexpr float PB_REAL = 0.5f / 512.0f;
constexpr float PB_DUM  = 0.5f;
constexpr float FI      = (float)(1.0 / 1.1); // GAMMA/(GAMMA+EPSILON)
constexpr float STOPERR = 1e-6f;
constexpr int   MAXIT   = 1000;
constexpr float LOG2E   = 1.4426950408889634f;
constexpr float CQ      = 10.0f * LOG2E;      // (1/EPSILON)*log2(e)
constexpr float LN2     = 0.6931471805599453f;

// V64 (r14-proven) cooperative config: 256 blocks x 1024 threads, 1 block/CU.
constexpr int BLOCKS  = 256;
constexpr int THREADS = 1024;
constexpr int WPB     = 16;                  // waves per block
constexpr int NWV     = BLOCKS * WPB;        // 4096 waves
constexpr int RPW     = NROWS / NWV;         // 32 rows per wave
constexpr int NP      = RPW / 2;             // 16 row-pairs per wave

// V32 config: 512 blocks x 1024 threads = 2 blocks/CU (needs VGPR<=32).
constexpr int NB2     = 512;
constexpr int NWV2    = NB2 * WPB;           // 8192 waves
constexpr int RPW2    = NROWS / NWV2;        // 16 rows per wave

// Streaming ring (V64): DP row-PAIRS in flight via 16B global_load_lds.
constexpr int DP     = 3;                    // pairs in flight
constexpr int ROWB   = 1536;                 // 512 cols x 3 B
constexpr int PAIRB  = 2 * ROWB;             // 3072 B = 3 glds16 chunks
constexpr int RING_B = DP * PAIRB;           // 9216 B per wave
constexpr size_t LDS_RING  = (size_t)WPB * RING_B;        // 147456
constexpr size_t LDS_TOTAL = LDS_RING + WPB * RPW * 4;    // + a_lds = 149504

// Workspace layout (floats), ~1.06 MB (proven safe).
constexpr size_t OFF_LSE = 0;                        // [NROWS] row logsumexp
constexpr size_t OFF_A   = (size_t)NROWS;            // [NROWS] scaling a
constexpr int    KPAD    = 520;
constexpr size_t OFF_B0  = 2 * (size_t)NROWS;        // [KPAD] b ping  (sc-only)
constexpr size_t OFF_B1  = OFF_B0 + KPAD;            // [KPAD] b pong  (sc-only)
constexpr size_t OFF_BF  = OFF_B0 + 2 * KPAD;        // [KPAD] b final
constexpr size_t OFF_EP  = OFF_B0 + 3 * KPAD;        // [KPAD] diff^2  (sc-only)

// d_out tail (d_out = 256 MiB): q24 = [0, 192 MiB) (wave-permuted rows);
// colp (KP1*512 floats, serves both variants) at 192 MiB; barrier at 200 MiB.
constexpr size_t COLP_BYTE_OFF = 192ull * 1024 * 1024;
constexpr size_t BAR_BYTE_OFF  = 200ull * 1024 * 1024;

#define WAITVM(N) do { asm volatile("s_waitcnt vmcnt(" #N ")" ::: "memory"); \
                       __builtin_amdgcn_sched_barrier(0); } while (0)
#define WAITLG() do { asm volatile("s_waitcnt lgkmcnt(0)" ::: "memory"); \
                      __builtin_amdgcn_sched_barrier(0); } while (0)

__device__ __forceinline__ void glds16(const void* g, void* l) {
  __builtin_amdgcn_global_load_lds(
      (const __attribute__((address_space(1))) void*)g,
      (__attribute__((address_space(3))) void*)l, 16, 0, 0);
}

// Nontemporal dword load: no-allocate in L2 -> streams from L3 without
// consuming the per-XCD L2 fill port (the hypothesized 2.5 TB/s wall).
__device__ __forceinline__ unsigned ntload(const unsigned* p) {
  return __builtin_nontemporal_load(p);
}

__device__ __forceinline__ float waveReduceSum(float v) {
#pragma unroll
  for (int s = 32; s >= 1; s >>= 1) v += __shfl_xor(v, s);
  return v;
}
__device__ __forceinline__ float waveReduceMax(float v) {
#pragma unroll
  for (int s = 32; s >= 1; s >>= 1) v = fmaxf(v, __shfl_xor(v, s));
  return v;
}

// device-coherent (agent-scope) accessors: bypass non-coherent L2, hit LLC.
__device__ __forceinline__ float scload(const float* p) {
  return __hip_atomic_load(p, __ATOMIC_RELAXED, __HIP_MEMORY_SCOPE_AGENT);
}
__device__ __forceinline__ void scstore(float* p, float v) {
  __hip_atomic_store(p, v, __ATOMIC_RELAXED, __HIP_MEMORY_SCOPE_AGENT);
}

// 4 x 24-bit values (top 24 bits of +0x80-rounded f32) packed into 3 dwords.
__device__ __forceinline__ void pack_chunk(const unsigned u[4], unsigned w[3]) {
  w[0] = u[0] | (u[1] << 24);
  w[1] = (u[1] >> 8) | (u[2] << 16);
  w[2] = (u[2] >> 16) | (u[3] << 8);
}
__device__ __forceinline__ void unpack_chunk(const unsigned* p, float q[4]) {
  unsigned a0 = p[0], a1 = p[1], a2 = p[2];
  q[0] = __uint_as_float(a0 << 8);
  q[1] = __uint_as_float(((a0 >> 16) & 0x0000FF00u) | (a1 << 16));
  q[2] = __uint_as_float(((a1 >> 8) & 0x00FFFF00u) | (a2 << 24));
  q[3] = __uint_as_float(a2 & 0xFFFFFF00u);
}
__device__ __forceinline__ void unpackR(unsigned a0, unsigned a1, unsigned a2,
                                        float q[4]) {
  q[0] = __uint_as_float(a0 << 8);
  q[1] = __uint_as_float(((a0 >> 16) & 0x0000FF00u) | (a1 << 16));
  q[2] = __uint_as_float(((a1 >> 8) & 0x00FFFF00u) | (a2 << 24));
  q[3] = __uint_as_float(a2 & 0xFFFFFF00u);
}

// ---------------------------------------------------------------------------
// Kernel 1: per-row logsumexp + packed 24-bit Q (3 B/elt; lane l's chunks at
// bytes 12l [cols 4l..4l+3] and 768+12l [cols 256+4l..256+4l+3]; rows stored
// in PER-WAVE STREAMING ORDER: row r at ((r % 4096)*32 + r/4096) * 1536;
// consumable by both 4096-wave (48KB/wave) and 8192-wave (24KB/wave) grids)
// + loop-state init.
// ---------------------------------------------------------------------------
__global__ __launch_bounds__(1024) void lse_q_init_kernel(
    const float* __restrict__ logits, float* __restrict__ ws,
    unsigned char* __restrict__ q24, unsigned* __restrict__ bar) {
  float* lse = ws + OFF_LSE;
  const int nw   = (gridDim.x * blockDim.x) >> 6;
  const int gw   = (blockIdx.x * blockDim.x + threadIdx.x) >> 6;
  const int lane = threadIdx.x & 63;

  for (int r = gw; r < NROWS; r += nw) {
    const float4* row4 = reinterpret_cast<const float4*>(logits + (size_t)r * KCOLS);
    float4 x0 = row4[lane];
    float4 x1 = row4[64 + lane];
    float m = fmaxf(fmaxf(fmaxf(x0.x, x0.y), fmaxf(x0.z, x0.w)),
                    fmaxf(fmaxf(x1.x, x1.y), fmaxf(x1.z, x1.w)));
    m = waveReduceMax(m);
    float s = exp2f((x0.x - m) * LOG2E) + exp2f((x0.y - m) * LOG2E)
            + exp2f((x0.z - m) * LOG2E) + exp2f((x0.w - m) * LOG2E)
            + exp2f((x1.x - m) * LOG2E) + exp2f((x1.y - m) * LOG2E)
            + exp2f((x1.z - m) * LOG2E) + exp2f((x1.w - m) * LOG2E);
    s = waveReduceSum(s);
    float L = m + log2f(s) * LN2;
    if (lane == 0) lse[r] = L;
    unsigned uA[4], uB[4];
    uA[0] = (__float_as_uint(exp2f((x0.x - L) * CQ)) + 0x80u) >> 8;
    uA[1] = (__float_as_uint(exp2f((x0.y - L) * CQ)) + 0x80u) >> 8;
    uA[2] = (__float_as_uint(exp2f((x0.z - L) * CQ)) + 0x80u) >> 8;
    uA[3] = (__float_as_uint(exp2f((x0.w - L) * CQ)) + 0x80u) >> 8;
    uB[0] = (__float_as_uint(exp2f((x1.x - L) * CQ)) + 0x80u) >> 8;
    uB[1] = (__float_as_uint(exp2f((x1.y - L) * CQ)) + 0x80u) >> 8;
    uB[2] = (__float_as_uint(exp2f((x1.z - L) * CQ)) + 0x80u) >> 8;
    uB[3] = (__float_as_uint(exp2f((x1.w - L) * CQ)) + 0x80u) >> 8;
    unsigned wA[3], wB[3];
    pack_chunk(uA, wA);
    pack_chunk(uB, wB);
    // wave-permuted row offset: consumer wave (r % 4096), slot (r / 4096)
    size_t ro = ((size_t)(r & 4095) * 32 + (size_t)(r >> 12)) * ROWB;
    unsigned* pA = (unsigned*)(q24 + ro + 12 * lane);        // cols 4l..4l+3
    unsigned* pB = (unsigned*)(q24 + ro + 768 + 12 * lane);  // cols 256+4l..
    pA[0] = wA[0]; pA[1] = wA[1]; pA[2] = wA[2];
    pB[0] = wB[0]; pB[1] = wB[1]; pB[2] = wB[2];
  }
  if (blockIdx.x == 0 && threadIdx.x < KP1)
    ws[OFF_B0 + threadIdx.x] = 1.0f / 513.0f;
  if (blockIdx.x == 0 && threadIdx.x == 0) {
    bar[0]  = 0u;   // arrival counter (cumulative)
    bar[32] = 0u;   // generation
  }
}

// ---------------------------------------------------------------------------
// Kernel 2a "V32" (cooperative, 512 blocks, 2 blocks/CU = 32 waves/CU):
// r15-proven minimal-register phase A; THIS ROUND: Q loads are NONTEMPORAL
// (L2 no-allocate) to test the L2-fill-port-ceiling hypothesis. Selected
// only if spill-free at <=32 VGPR and occupancy >= 2; else V64 runs.
// ---------------------------------------------------------------------------
__global__ __launch_bounds__(THREADS, 8) void sinkhorn_v32(
    const unsigned char* __restrict__ q24, float* __restrict__ ws,
    float* __restrict__ colp, unsigned* __restrict__ bar) {
  float* a    = ws + OFF_A;
  float* b0   = ws + OFF_B0;
  float* b1   = ws + OFF_B1;
  float* bfin = ws + OFF_BF;
  float* ep   = ws + OFF_EP;
  unsigned* cnt = bar;
  unsigned* gen = bar + 32;

  __shared__ float lds2[WPB][KPAD];   // 16*520*4 = 33,280 B
  __shared__ float s_err;
  __shared__ int   s_nbar;
  __shared__ int   s_dead;

  const int tid  = threadIdx.x;
  const int wv   = tid >> 6;
  const int lane = tid & 63;
  const int bk   = blockIdx.x;
  const int gw   = bk * WPB + wv;        // global wave id [0, 8192)
  const int v4   = gw & 4095;
  const int hi   = gw >> 12;             // 0 or 1
  // this wave's 16 rows: contiguous 24KB half-block of the permuted layout
  const unsigned char* gsv = q24 + ((size_t)v4 * 32 + (size_t)hi * 16) * ROWB;
  const int rA = v4 + hi * 65536;        // physical row of slot s: rA + s*4096

  if (tid == 0) { s_nbar = 0; s_dead = 0; }
  __syncthreads();

  auto gridBar = [&]() {
    __syncthreads();
    if (tid == 0) {
      int nb = s_nbar;
      unsigned old = atomicAdd(cnt, 1u);
      if (old == (unsigned)(nb * NB2 + (NB2 - 1))) {
        atomicAdd(gen, 1u);
      } else if (!s_dead) {
        int spins = 0;
        while (__hip_atomic_load(gen, __ATOMIC_RELAXED, __HIP_MEMORY_SCOPE_AGENT)
               <= (unsigned)nb) {
          __builtin_amdgcn_s_sleep(1);
          if (++spins > (1 << 24)) { s_dead = 1; break; }  // fail-fast
        }
      }
      s_nbar = nb + 1;
    }
    __syncthreads();
  };

  float err = 1.0f;
  int it = 0;
  for (; it < MAXIT; ++it) {
    if (!(err > STOPERR)) break;   // NaN err also stops (matches JAX)

    const float* bcv = (it & 1) ? b1 : b0;
    float*       bnv = (it & 1) ? b0 : b1;

    // stage current b: lane l holds b[4l..4l+3], b[256+4l..256+4l+3], b[512]
    float rb[8];
#pragma unroll
    for (int e = 0; e < 4; ++e) {
      rb[e]     = scload(&bcv[4 * lane + e]);
      rb[4 + e] = scload(&bcv[256 + 4 * lane + e]);
    }
    float bdum = scload(&bcv[512]);

    // ---- phase A: 16 rows, nontemporal Q loads (L2 no-allocate) ----
    float cp[8] = {0.f, 0.f, 0.f, 0.f, 0.f, 0.f, 0.f, 0.f};
    float adum = 0.f;
#pragma unroll 1
    for (int s = 0; s < RPW2; ++s) {
      const unsigned* pa =
          (const unsigned*)(gsv + (size_t)s * ROWB + 12 * lane);
      unsigned c0 = ntload(pa), c1 = ntload(pa + 1), c2 = ntload(pa + 2);
      unsigned d0w = ntload(pa + 192), d1w = ntload(pa + 193),
               d2w = ntload(pa + 194);
      float q[8];
      unpackR(c0, c1, c2, q);
      unpackR(d0w, d1w, d2w, q + 4);
      float d = 0.f;
#pragma unroll
      for (int e = 0; e < 8; ++e) d = fmaf(q[e], rb[e], d);
#pragma unroll
      for (int s2 = 32; s2 >= 1; s2 >>= 1) d += __shfl_xor(d, s2);
      float ai = PA / (d + bdum);
      if (lane == 0) a[rA + (s << 12)] = ai;
#pragma unroll
      for (int e = 0; e < 8; ++e) cp[e] = fmaf(ai, q[e], cp[e]);
      adum += ai;
    }

    // ---- combine 16 waves' partials (2-way-free layout) ----
#pragma unroll
    for (int e = 0; e < 4; ++e) {
      lds2[wv][4 * lane + e]       = cp[e];
      lds2[wv][256 + 4 * lane + e] = cp[4 + e];
    }
    if (lane == 0) lds2[wv][512] = adum;
    __syncthreads();
    for (int t = tid; t < KP1; t += THREADS) {
      float s = 0.f;
#pragma unroll
      for (int w2 = 0; w2 < WPB; ++w2) s += lds2[w2][t];
      scstore(&colp[(size_t)t * NB2 + bk], s);
    }
    gridBar();

    // ---- phase B: jcol = bk (+ col 512 on blk0/wv1) ----
    {
      const int jcol = bk + wv * NB2;
      if (jcol < KP1) {
        float s = 0.f;
#pragma unroll
        for (int e = 0; e < NB2 / 64; ++e)
          s += scload(&colp[(size_t)jcol * NB2 + 64 * e + lane]);
        s = waveReduceSum(s);
        if (lane == 0) {
          float bj = (jcol < KCOLS) ? powf(PB_REAL / s, FI) : (PB_DUM / s);
          scstore(&bnv[jcol], bj);
          float d = bj - scload(&bcv[jcol]);
          scstore(&ep[jcol], d * d);
        }
      }
    }
    gridBar();

    // ---- err: identical fixed-order reduction in every block ----
    if (wv == 0) {
      float s0 = 0.f;
      for (int t = lane; t < KP1; t += 64) s0 += scload(&ep[t]);
      s0 = waveReduceSum(s0);
      if (lane == 0) s_err = sqrtf(s0);
    }
    __syncthreads();
    err = s_err;
  }

  if (bk == 0) {
    const float* bf = (it & 1) ? b1 : b0;
    for (int t = tid; t < KP1; t += THREADS) bfin[t] = scload(&bf[t]);
  }
}

// ---------------------------------------------------------------------------
// Kernel 2b "V64" (r14-proven, byte-identical fallback): 3-pair glds16 ring,
// counted vmcnt, lgkmcnt race fence, stride-12 conflict-free unpack reads.
// ---------------------------------------------------------------------------
extern __shared__ char smem[];

__global__ __launch_bounds__(THREADS) void sinkhorn_loop(
    const unsigned char* __restrict__ q24, float* __restrict__ ws,
    float* __restrict__ colp, unsigned* __restrict__ bar) {
  float* a    = ws + OFF_A;
  float* b0   = ws + OFF_B0;
  float* b1   = ws + OFF_B1;
  float* bfin = ws + OFF_BF;
  float* ep   = ws + OFF_EP;
  unsigned* cnt = bar;
  unsigned* gen = bar + 32;

  __shared__ float s_err;
  __shared__ int   s_nbar;
  __shared__ int   s_dead;

  const int tid  = threadIdx.x;
  const int wv   = tid >> 6;
  const int lane = tid & 63;
  const int bk   = blockIdx.x;
  const int gw   = bk * WPB + wv;   // global wave id [0, 4096)

  char*  ring  = smem + wv * RING_B;
  float* a_lds = (float*)(smem + LDS_RING) + wv * RPW;
  float (*lds2)[KPAD] = (float(*)[KPAD])smem;   // combine overlay (33 KB)

  const char* gwave = (const char*)q24 + (size_t)gw * RPW * ROWB;  // 48 KB block

  if (tid == 0) { s_nbar = 0; s_dead = 0; }
  __syncthreads();

  auto gridBar = [&]() {
    __syncthreads();
    if (tid == 0) {
      int nb = s_nbar;
      unsigned old = atomicAdd(cnt, 1u);
      if (old == (unsigned)(nb * BLOCKS + (BLOCKS - 1))) {
        atomicAdd(gen, 1u);
      } else if (!s_dead) {
        int spins = 0;
        while (__hip_atomic_load(gen, __ATOMIC_RELAXED, __HIP_MEMORY_SCOPE_AGENT)
               <= (unsigned)nb) {
          __builtin_amdgcn_s_sleep(1);
          if (++spins > (1 << 24)) { s_dead = 1; break; }  // fail-fast
        }
      }
      s_nbar = nb + 1;
    }
    __syncthreads();
  };

  float err = 1.0f;
  int it = 0;
  for (; it < MAXIT; ++it) {
    if (!(err > STOPERR)) break;   // NaN err also stops (matches JAX)

    const float* bcv = (it & 1) ? b1 : b0;
    float*       bnv = (it & 1) ? b0 : b1;

    float rb[8];
#pragma unroll
    for (int e = 0; e < 4; ++e) {
      rb[e]     = scload(&bcv[4 * lane + e]);
      rb[4 + e] = scload(&bcv[256 + 4 * lane + e]);
    }
    float bdum = scload(&bcv[512]);

#pragma unroll
    for (int s = 0; s < DP; ++s) {
      const char* g = gwave + (size_t)s * PAIRB;
      char* lsl = ring + s * PAIRB;
      glds16(g + 16 * lane,        lsl);
      glds16(g + 1024 + 16 * lane, lsl + 1024);
      glds16(g + 2048 + 16 * lane, lsl + 2048);
    }

    float cp[8] = {0.f, 0.f, 0.f, 0.f, 0.f, 0.f, 0.f, 0.f};
    float adum = 0.f;
    int so = 0;
#pragma unroll 1
    for (int p = 0; p < NP; ++p) {
      if (p <= NP - 3)      WAITVM(6);
      else if (p == NP - 2) WAITVM(3);
      else                  WAITVM(0);

      const char* sl = ring + so * PAIRB;
      float q0[8], q1[8];
      unpack_chunk((const unsigned*)(sl + 12 * lane),              q0);
      unpack_chunk((const unsigned*)(sl + 768 + 12 * lane),        q0 + 4);
      unpack_chunk((const unsigned*)(sl + ROWB + 12 * lane),       q1);
      unpack_chunk((const unsigned*)(sl + ROWB + 768 + 12 * lane), q1 + 4);
      WAITLG();   // HW fence: reads retired before same-slot refill DMA

      if (p + DP < NP) {
        const char* g = gwave + (size_t)(p + DP) * PAIRB;
        char* lsl = ring + so * PAIRB;
        glds16(g + 16 * lane,        lsl);
        glds16(g + 1024 + 16 * lane, lsl + 1024);
        glds16(g + 2048 + 16 * lane, lsl + 2048);
      }

      float d0 = 0.f, d1 = 0.f;
#pragma unroll
      for (int e = 0; e < 8; ++e) {
        d0 = fmaf(q0[e], rb[e], d0);
        d1 = fmaf(q1[e], rb[e], d1);
      }
#pragma unroll
      for (int s = 32; s >= 1; s >>= 1) {
        d0 += __shfl_xor(d0, s);
        d1 += __shfl_xor(d1, s);
      }
      float ai0 = PA / (d0 + bdum);
      float ai1 = PA / (d1 + bdum);
      if (lane == 0) { a_lds[2 * p] = ai0; a_lds[2 * p + 1] = ai1; }
#pragma unroll
      for (int e = 0; e < 8; ++e) {
        cp[e] = fmaf(ai0, q0[e], cp[e]);
        cp[e] = fmaf(ai1, q1[e], cp[e]);
      }
      adum += ai0 + ai1;
      so = (so == DP - 1) ? 0 : so + 1;
    }

    if (lane < RPW) a[gw + lane * NWV] = a_lds[lane];
    __syncthreads();

#pragma unroll
    for (int e = 0; e < 4; ++e) {
      lds2[wv][4 * lane + e]       = cp[e];
      lds2[wv][256 + 4 * lane + e] = cp[4 + e];
    }
    if (lane == 0) lds2[wv][512] = adum;
    __syncthreads();
    for (int t = tid; t < KP1; t += THREADS) {
      float s = 0.f;
#pragma unroll
      for (int w2 = 0; w2 < WPB; ++w2) s += lds2[w2][t];
      scstore(&colp[(size_t)t * BLOCKS + bk], s);
    }
    gridBar();

    {
      const int jcol = bk + wv * BLOCKS;
      if (jcol < KP1) {
        float s = 0.f;
#pragma unroll
        for (int e = 0; e < BLOCKS / 64; ++e)
          s += scload(&colp[(size_t)jcol * BLOCKS + 64 * e + lane]);
        s = waveReduceSum(s);
        if (lane == 0) {
          float bj = (jcol < KCOLS) ? powf(PB_REAL / s, FI) : (PB_DUM / s);
          scstore(&bnv[jcol], bj);
          float d = bj - scload(&bcv[jcol]);
          scstore(&ep[jcol], d * d);
        }
      }
    }
    gridBar();

    if (wv == 0) {
      float s0 = 0.f;
      for (int t = lane; t < KP1; t += 64) s0 += scload(&ep[t]);
      s0 = waveReduceSum(s0);
      if (lane == 0) s_err = sqrtf(s0);
    }
    __syncthreads();
    err = s_err;
  }

  if (bk == 0) {
    const float* bf = (it & 1) ? b1 : b0;
    for (int t = tid; t < KP1; t += THREADS) bfin[t] = scload(&bf[t]);
  }
}

// ---------------------------------------------------------------------------
// Kernel 3: plan = n * a * Q * b^T, recomputing Q in f32 from logits+lse
// (d_out, which held the packed Q + loop scratch, is overwritten).
// ---------------------------------------------------------------------------
__global__ __launch_bounds__(1024) void plan_epilogue(
    const float* __restrict__ logits, const float* __restrict__ ws,
    float* __restrict__ out) {
  const float* lse  = ws + OFF_LSE;
  const float* a    = ws + OFF_A;
  const float* bfin = ws + OFF_BF;
  const int nw   = (gridDim.x * blockDim.x) >> 6;
  const int gw   = (blockIdx.x * blockDim.x + threadIdx.x) >> 6;
  const int lane = threadIdx.x & 63;

  const float4* b4 = reinterpret_cast<const float4*>(bfin);
  float4 rb0 = b4[lane];        // b[4l..4l+3]
  float4 rb1 = b4[64 + lane];   // b[256+4l..256+4l+3]

  for (int r = gw; r < NROWS; r += nw) {
    const float4* row4 = reinterpret_cast<const float4*>(logits + (size_t)r * KCOLS);
    float4*       out4 = reinterpret_cast<float4*>(out + (size_t)r * KCOLS);
    float L  = lse[r];
    float na = a[r] * (float)NROWS;   // n * a_i
    float4 x0 = row4[lane];
    float4 x1 = row4[64 + lane];
    float4 o0, o1;
    o0.x = na * exp2f((x0.x - L) * CQ) * rb0.x;
    o0.y = na * exp2f((x0.y - L) * CQ) * rb0.y;
    o0.z = na * exp2f((x0.z - L) * CQ) * rb0.z;
    o0.w = na * exp2f((x0.w - L) * CQ) * rb0.w;
    o1.x = na * exp2f((x1.x - L) * CQ) * rb1.x;
    o1.y = na * exp2f((x1.y - L) * CQ) * rb1.y;
    o1.z = na * exp2f((x1.z - L) * CQ) * rb1.z;
    o1.w = na * exp2f((x1.w - L) * CQ) * rb1.w;
    out4[lane]      = o0;
    out4[64 + lane] = o1;
  }
}

extern "C" void kernel_launch(void* const* d_in, const int* in_sizes, int n_in,
                              void* d_out, int out_size, void* d_ws, size_t ws_size,
                              hipStream_t stream) {
  (void)in_sizes; (void)n_in; (void)out_size; (void)ws_size;
  const float*   logits = (const float*)d_in[0];
  float*         out    = (float*)d_out;
  float*         ws     = (float*)d_ws;    // ~1.06 MB (proven safe)
  unsigned char* q24    = (unsigned char*)d_out;                     // 192 MiB
  float*         colp   = (float*)((char*)d_out + COLP_BYTE_OFF);    // ~1 MiB
  unsigned*      bar    = (unsigned*)((char*)d_out + BAR_BYTE_OFF);  // 132 B

  hipLaunchKernelGGL(lse_q_init_kernel, dim3(1024), dim3(1024), 0, stream,
                     logits, ws, q24, bar);

  const unsigned char* qArg  = q24;
  float*               wsArg = ws;
  float*               cpArg = colp;
  unsigned*            brArg = bar;
  void* args[] = { (void*)&qArg, (void*)&wsArg, (void*)&cpArg, (void*)&brArg };

  // Select V32 (512 blocks, 32 waves/CU) ONLY if it compiled spill-free and
  // the runtime grants 2 blocks/CU (r15: it did). Fallback = r14-proven V64.
  bool useV32 = false;
  hipFuncAttributes fa;
  if (hipFuncGetAttributes(&fa, (const void*)sinkhorn_v32) == hipSuccess &&
      fa.localSizeBytes == 0) {
    int nb = 0;
    if (hipOccupancyMaxActiveBlocksPerMultiprocessor(
            &nb, (const void*)sinkhorn_v32, THREADS, 0) == hipSuccess &&
        nb >= 2) {
      useV32 = true;
    }
  }

  if (useV32) {
    hipLaunchCooperativeKernel((void*)sinkhorn_v32, dim3(NB2), dim3(THREADS),
                               args, 0, stream);
  } else {
    (void)hipFuncSetAttribute((const void*)sinkhorn_loop,
                              hipFuncAttributeMaxDynamicSharedMemorySize,
                              (int)LDS_TOTAL);
    hipLaunchCooperativeKernel((void*)sinkhorn_loop, dim3(BLOCKS), dim3(THREADS),
                               args, (unsigned)LDS_TOTAL, stream);
  }

  hipLaunchKernelGGL(plan_epilogue, dim3(2048), dim3(1024), 0, stream,
                     logits, ws, out);
}